// Round 10
// baseline (764.356 us; speedup 1.0000x reference)
//
#include <hip/hip_runtime.h>
#include <math.h>

#define NEG_SLOPE 0.2f

typedef __attribute__((ext_vector_type(8))) short short8;
typedef __attribute__((ext_vector_type(4))) float floatx4;

// ---------------- fp32 <-> bf16 split helpers (RNE) ----------------
__device__ __forceinline__ unsigned short f2bf(float f) {
    unsigned u = __float_as_uint(f);
    u += 0x7fffu + ((u >> 16) & 1u);
    return (unsigned short)(u >> 16);
}
__device__ __forceinline__ float bf2f(unsigned short h) {
    return __uint_as_float((unsigned)h << 16);
}
__device__ __forceinline__ float lrelu(float v) {
    return v > 0.f ? v : NEG_SLOPE * v;
}

// ---- async global->LDS, 16B per lane (gfx950). dest = uniform base + lane*16
typedef __attribute__((address_space(3))) unsigned int lds_u32;
typedef const __attribute__((address_space(1))) unsigned int glb_u32c;
__device__ __forceinline__ void gll16(const unsigned short* g, unsigned short* l) {
    __builtin_amdgcn_global_load_lds((glb_u32c*)g, (lds_u32*)l, 16, 0, 0);
}

// ---------------- fused weight pre-pass: 8 jobs in one launch ----------------
struct SJob { const float* W; unsigned short* Th; unsigned short* Tl; int K, N, Kp, base; };
struct SJobs { SJob j[8]; };

__global__ __launch_bounds__(256) void split_transpose_multi(SJobs js) {
    int t = blockIdx.x;
    int ji = 0;
#pragma unroll
    for (int q = 1; q < 8; ++q) if (t >= js.j[q].base) ji = q;
    const SJob jb = js.j[ji];
    int local = t - jb.base;
    int ntiles = jb.N / 32;
    int tn = local % ntiles, tk = local / ntiles;
    int k0 = tk * 32, n0 = tn * 32;
    __shared__ float tbuf[32][33];
    int c = threadIdx.x & 31, r = threadIdx.x >> 5;
    for (int rr = r; rr < 32; rr += 8) {
        int k = k0 + rr, n = n0 + c;
        tbuf[rr][c] = (k < jb.K && n < jb.N) ? jb.W[(long)k * jb.N + n] : 0.f;
    }
    __syncthreads();
    for (int rr = r; rr < 32; rr += 8) {
        int n = n0 + rr, k = k0 + c;
        if (n < jb.N && k < jb.Kp) {
            float v = tbuf[c][rr];
            unsigned short h = f2bf(v);
            jb.Th[(long)n * jb.Kp + k] = h;
            jb.Tl[(long)n * jb.Kp + k] = f2bf(v - bf2f(h));
        }
    }
}

// ---- cell_x row split: [M][735] fp32 -> [M][736] bf16 hi/lo (zero-pad) ----
__global__ __launch_bounds__(256) void split_cell_rows(
    const float* __restrict__ X, unsigned short* __restrict__ H,
    unsigned short* __restrict__ L, int M)
{
    long i = blockIdx.x;
    int t = threadIdx.x;
    const float* r = X + i * 735;
    for (int c = t; c < 736; c += 256) {
        float v = (c < 735) ? r[c] : 0.f;
        unsigned short h = f2bf(v);
        H[i * 736 + c] = h;
        L[i * 736 + c] = f2bf(v - bf2f(h));
    }
}

// ---- 4 fused matvecs: wa[k] = sum_n W[k][n]*a[n] (k in [0,256) each) ----
__global__ __launch_bounds__(256) void matvec4(
    const float* __restrict__ gdW, const float* __restrict__ gdas, const float* __restrict__ gdad,
    float* __restrict__ wds, float* __restrict__ wdd,
    const float* __restrict__ g1W, const float* __restrict__ g1as, const float* __restrict__ g1ad,
    float* __restrict__ w1s, float* __restrict__ w1d)
{
    int b = blockIdx.x;
    int sel = b >> 8, k = b & 255, t = threadIdx.x;
    const float *W, *a; float* o; int N;
    if (sel == 0)      { W = gdW; a = gdas; o = wds; N = 256; }
    else if (sel == 1) { W = gdW; a = gdad; o = wdd; N = 256; }
    else if (sel == 2) { W = g1W; a = g1as; o = w1s; N = 1024; }
    else               { W = g1W; a = g1ad; o = w1d; N = 1024; }
    float s = 0.f;
    for (int n = t; n < N; n += 256) s += W[(long)k * N + n] * a[n];
#pragma unroll
    for (int off = 32; off; off >>= 1) s += __shfl_down(s, off);
    __shared__ float ls[4];
    if ((t & 63) == 0) ls[t >> 6] = s;
    __syncthreads();
    if (t == 0) o[k] = ls[0] + ls[1] + ls[2] + ls[3];
}

// ======== dedicated d0 kernel: M x 128 @ 128 x 256, no LDS, no barriers ======
__global__ __launch_bounds__(256, 3) void gemm_d0_fused(
    const float* __restrict__ A,                    // [M][128] fp32
    const unsigned short* __restrict__ Bh_g,        // [256][128] bf16-hi
    const unsigned short* __restrict__ Bl_g,        // [256][128] bf16-lo
    const float* __restrict__ bias,                 // [256]
    const float* __restrict__ was, const float* __restrict__ wad, // [256]
    float* __restrict__ C,                          // [M][256] fp32 (relu'd)
    float* __restrict__ das, float* __restrict__ dad,
    int M, int nblk)
{
    int bid = blockIdx.x;
    int q = nblk >> 3, rr = nblk & 7;
    int xcd = bid & 7, idx = bid >> 3;
    int wg = (xcd < rr ? xcd * (q + 1) : rr * (q + 1) + (xcd - rr) * q) + idx;
    int rb = wg >> 1, colh = wg & 1;
    int m0 = rb * 64, n0 = colh * 128;
    if (m0 >= M) return;
    const int tid = threadIdx.x;
    const int wave = tid >> 6, lane = tid & 63;
    const int lm = lane & 15, lq = lane >> 4;
    const int wn = n0 + wave * 32;

    floatx4 acc[4][2];
    floatx4 zero = {0.f, 0.f, 0.f, 0.f};
#pragma unroll
    for (int i = 0; i < 4; ++i)
#pragma unroll
        for (int j = 0; j < 2; ++j) acc[i][j] = zero;

#pragma unroll
    for (int ks = 0; ks < 4; ++ks) {
        const int kc = ks * 32 + lq * 8;
        short8 bh[2], bl[2];
#pragma unroll
        for (int j = 0; j < 2; ++j) {
            long bo = (long)(wn + j * 16 + lm) * 128 + kc;
            bh[j] = *(const short8*)(Bh_g + bo);
            bl[j] = *(const short8*)(Bl_g + bo);
        }
        short8 ah[4], al[4];
#pragma unroll
        for (int i = 0; i < 4; ++i) {
            int gm = m0 + i * 16 + lm;
            float4 t0 = {0.f, 0.f, 0.f, 0.f}, t1 = {0.f, 0.f, 0.f, 0.f};
            if (gm < M) {
                const float* ap = A + (long)gm * 128 + kc;
                t0 = *(const float4*)ap;
                t1 = *(const float4*)(ap + 4);
            }
            short8 h, l;
            float f;
            f = t0.x; h[0] = f2bf(f); l[0] = f2bf(f - bf2f(h[0]));
            f = t0.y; h[1] = f2bf(f); l[1] = f2bf(f - bf2f(h[1]));
            f = t0.z; h[2] = f2bf(f); l[2] = f2bf(f - bf2f(h[2]));
            f = t0.w; h[3] = f2bf(f); l[3] = f2bf(f - bf2f(h[3]));
            f = t1.x; h[4] = f2bf(f); l[4] = f2bf(f - bf2f(h[4]));
            f = t1.y; h[5] = f2bf(f); l[5] = f2bf(f - bf2f(h[5]));
            f = t1.z; h[6] = f2bf(f); l[6] = f2bf(f - bf2f(h[6]));
            f = t1.w; h[7] = f2bf(f); l[7] = f2bf(f - bf2f(h[7]));
            ah[i] = h; al[i] = l;
        }
#pragma unroll
        for (int i = 0; i < 4; ++i)
#pragma unroll
            for (int j = 0; j < 2; ++j) {
                acc[i][j] = __builtin_amdgcn_mfma_f32_16x16x32_bf16(ah[i], bh[j], acc[i][j], 0, 0, 0);
                acc[i][j] = __builtin_amdgcn_mfma_f32_16x16x32_bf16(al[i], bh[j], acc[i][j], 0, 0, 0);
                acc[i][j] = __builtin_amdgcn_mfma_f32_16x16x32_bf16(ah[i], bl[j], acc[i][j], 0, 0, 0);
            }
    }

    // ---- epilogue: bias+relu, store C, fused att-scalar partials ----
    __shared__ float sps[64][5], spd[64][5];
    float bv[2], wsv[2], wdv[2];
#pragma unroll
    for (int j = 0; j < 2; ++j) {
        int gn = wn + j * 16 + lm;
        bv[j] = bias[gn];
        wsv[j] = was[gn];
        wdv[j] = wad[gn];
    }
#pragma unroll
    for (int i = 0; i < 4; ++i) {
#pragma unroll
        for (int r = 0; r < 4; ++r) {
            int gm = m0 + i * 16 + lq * 4 + r;
            float vs = 0.f, vd = 0.f;
#pragma unroll
            for (int j = 0; j < 2; ++j) {
                int gn = wn + j * 16 + lm;
                float v = fmaxf(acc[i][j][r] + bv[j], 0.f);
                if (gm < M) C[(long)gm * 256 + gn] = v;
                vs = fmaf(v, wsv[j], vs);
                vd = fmaf(v, wdv[j], vd);
            }
#pragma unroll
            for (int o = 8; o; o >>= 1) {
                vs += __shfl_xor(vs, o);
                vd += __shfl_xor(vd, o);
            }
            if (lm == 0) {
                sps[i * 16 + lq * 4 + r][wave] = vs;
                spd[i * 16 + lq * 4 + r][wave] = vd;
            }
        }
    }
    __syncthreads();
    if (tid < 64) {
        int gm = m0 + tid;
        if (gm < M) {
            float s = sps[tid][0] + sps[tid][1] + sps[tid][2] + sps[tid][3];
            float d2 = spd[tid][0] + spd[tid][1] + spd[tid][2] + spd[tid][3];
            atomicAdd(das + gm, s);
            atomicAdd(dad + gm, d2);
        }
    }
}

// ---------------- GEMM via split-bf16 MFMA ----------------------------------
// r10: counted-vmcnt pipeline (T4) on r9's 4-wave 64x128 geometry. r8+r9
// post-mortems: both converge at ~600 TF = m233's 2-phase plateau; the
// documented escape is never draining vmcnt in the loop (m218: +38-73%).
// Per K-step: s_waitcnt vmcnt(6) (tile t's 6 glls done, t+1's stay in
// flight) -> s_barrier -> ds_read+MFMA -> s_waitcnt lgkmcnt(0) (reads
// hardware-retired before buffer reuse) -> s_barrier -> issue t+2 glls
// into the just-freed buffer. Double-buffered 48KB LDS, 3 blocks/CU.
// Swizzle unchanged (r5: measured 0 conflicts).
template<int ACT, int OSPLIT>  // ACT: 0=none,1=relu,2=elu
__global__ __launch_bounds__(256, 3) void gemm2(
    const unsigned short* __restrict__ Ah_g, const unsigned short* __restrict__ Al_g,
    const unsigned short* __restrict__ Bh_g, const unsigned short* __restrict__ Bl_g,
    const float* __restrict__ bias,
    float* __restrict__ C, unsigned short* __restrict__ Ch_g, unsigned short* __restrict__ Cl_g,
    int M, int K, int N, int Kp, int Cs)
{
    __shared__ unsigned short Ah[2][2048];   // [64 rows][32 k] x2 buf
    __shared__ unsigned short Al[2][2048];
    __shared__ unsigned short Bh[2][4096];   // [128 rows][32 k] x2 buf
    __shared__ unsigned short Bl[2][4096];
    const int tid = threadIdx.x;
    const int wave = tid >> 6, lane = tid & 63;
    const int lm = lane & 15, lq = lane >> 4;
    const int wn = wave * 32;            // n-quarter within 128-col tile
    // ---- XCD swizzle (bijective over padded grid) ----
    const int nx = gridDim.x;
    const int lin = blockIdx.y * nx + blockIdx.x;
    const int sup = lin / (8 * nx);
    const int wit = lin - sup * 8 * nx;
    const int rowb = sup * 8 + (wit & 7);
    const int nb = wit >> 3;
    const int m0 = rowb * 64, n0 = nb * 128;
    if (m0 >= M) return;   // padded row-band

    floatx4 acc[4][2];
    floatx4 zero = {0.f, 0.f, 0.f, 0.f};
#pragma unroll
    for (int i = 0; i < 4; ++i)
#pragma unroll
        for (int j = 0; j < 2; ++j) acc[i][j] = zero;

    // ---- staging addresses (per-lane source, wave-uniform LDS chunk) ----
    const int srow = lane >> 2;                       // row within 16-row chunk
    const int sslot = (lane & 3) ^ ((lane >> 3) & 3); // pre-swizzled source slot
    const unsigned short* agh = Ah_g + (long)(m0 + wave * 16 + srow) * Kp + sslot * 8;
    const unsigned short* agl = Al_g + (long)(m0 + wave * 16 + srow) * Kp + sslot * 8;
    const unsigned short* bgh0 = Bh_g + (long)(n0 + wave * 32 + srow) * Kp + sslot * 8;
    const unsigned short* bgh1 = Bh_g + (long)(n0 + wave * 32 + 16 + srow) * Kp + sslot * 8;
    const unsigned short* bgl0 = Bl_g + (long)(n0 + wave * 32 + srow) * Kp + sslot * 8;
    const unsigned short* bgl1 = Bl_g + (long)(n0 + wave * 32 + 16 + srow) * Kp + sslot * 8;
    const int wchA = wave * 512;
    const int wchB = wave * 1024;
    const int xa = (lm >> 1) & 3;                     // read-side swizzle key

    // prologue: stage tile 0 -> buf0, tile 1 -> buf1 (6 glls per wave each)
    gll16(agh, &Ah[0][wchA]);
    gll16(agl, &Al[0][wchA]);
    gll16(bgh0, &Bh[0][wchB]);
    gll16(bgh1, &Bh[0][wchB + 512]);
    gll16(bgl0, &Bl[0][wchB]);
    gll16(bgl1, &Bl[0][wchB + 512]);
    if (32 < K) {
        gll16(agh + 32, &Ah[1][wchA]);
        gll16(agl + 32, &Al[1][wchA]);
        gll16(bgh0 + 32, &Bh[1][wchB]);
        gll16(bgh1 + 32, &Bh[1][wchB + 512]);
        gll16(bgl0 + 32, &Bl[1][wchB]);
        gll16(bgl1 + 32, &Bl[1][wchB + 512]);
    }
    int cur = 0;

    for (int k0 = 0; k0 < K; k0 += 32) {
        // wait tile t's 6 loads only (t+1's 6 stay in flight); last tile drains
        if (k0 + 32 < K) asm volatile("s_waitcnt vmcnt(6)" ::: "memory");
        else             asm volatile("s_waitcnt vmcnt(0)" ::: "memory");
        __builtin_amdgcn_s_barrier();            // all waves' tile-t data in LDS
        asm volatile("" ::: "memory");
        short8 fah[4], fal[4], fbh[2], fbl[2];
#pragma unroll
        for (int i = 0; i < 4; ++i) {
            int off = (i * 16 + lm) * 32 + ((lq ^ xa) << 3);
            fah[i] = *(const short8*)&Ah[cur][off];
            fal[i] = *(const short8*)&Al[cur][off];
        }
#pragma unroll
        for (int j = 0; j < 2; ++j) {
            int off = (wn + j * 16 + lm) * 32 + ((lq ^ xa) << 3);
            fbh[j] = *(const short8*)&Bh[cur][off];
            fbl[j] = *(const short8*)&Bl[cur][off];
        }
#pragma unroll
        for (int i = 0; i < 4; ++i)
#pragma unroll
            for (int j = 0; j < 2; ++j) {
                acc[i][j] = __builtin_amdgcn_mfma_f32_16x16x32_bf16(fah[i], fbh[j], acc[i][j], 0, 0, 0);
                acc[i][j] = __builtin_amdgcn_mfma_f32_16x16x32_bf16(fal[i], fbh[j], acc[i][j], 0, 0, 0);
                acc[i][j] = __builtin_amdgcn_mfma_f32_16x16x32_bf16(fah[i], fbl[j], acc[i][j], 0, 0, 0);
            }
        // retire this buffer's ds_reads in hardware before any wave overwrites it
        asm volatile("s_waitcnt lgkmcnt(0)" ::: "memory");
        __builtin_amdgcn_s_barrier();
        // issue tile t+2 into the buffer just freed (keeps 6-12 loads in flight)
        if (k0 + 64 < K) {
            gll16(agh + k0 + 64, &Ah[cur][wchA]);
            gll16(agl + k0 + 64, &Al[cur][wchA]);
            gll16(bgh0 + k0 + 64, &Bh[cur][wchB]);
            gll16(bgh1 + k0 + 64, &Bh[cur][wchB + 512]);
            gll16(bgl0 + k0 + 64, &Bl[cur][wchB]);
            gll16(bgl1 + k0 + 64, &Bl[cur][wchB + 512]);
        }
        cur ^= 1;
    }
    // ---- epilogue: C/D layout col=lane&15, row=quad*4+reg (m89-verified) ----
#pragma unroll
    for (int j = 0; j < 2; ++j) {
        int gn = n0 + wn + j * 16 + lm;
        float bv = bias ? bias[gn] : 0.f;
#pragma unroll
        for (int i = 0; i < 4; ++i) {
#pragma unroll
            for (int r = 0; r < 4; ++r) {
                int gm = m0 + i * 16 + lq * 4 + r;
                if (gm < M) {
                    float v = acc[i][j][r] + bv;
                    if (ACT == 1) v = fmaxf(v, 0.f);
                    if (ACT == 2) v = v > 0.f ? v : expm1f(v);
                    if (OSPLIT) {
                        long o = (long)gm * Cs + gn;
                        unsigned short h = f2bf(v);
                        Ch_g[o] = h;
                        Cl_g[o] = f2bf(v - bf2f(h));
                    } else {
                        C[(long)gm * (long)Cs + gn] = v;
                    }
                }
            }
        }
    }
}

// ---------------- per-node attention scalars (F=256) ----------------
__global__ __launch_bounds__(256) void att_scalars(
    const float* __restrict__ x, const float* __restrict__ avs,
    const float* __restrict__ avd, float* __restrict__ outs,
    float* __restrict__ outd, int F)
{
    const int i = blockIdx.x;
    const int t = threadIdx.x;
    float ps = 0.f, pd = 0.f;
    for (int f = t; f < F; f += 256) {
        float v = x[(long)i * F + f];
        ps += v * avs[f];
        pd += v * avd[f];
    }
#pragma unroll
    for (int off = 32; off; off >>= 1) {
        ps += __shfl_down(ps, off);
        pd += __shfl_down(pd, off);
    }
    __shared__ float ls[4], ld[4];
    int lane = t & 63, w = t >> 6;
    if (lane == 0) { ls[w] = ps; ld[w] = pd; }
    __syncthreads();
    if (t == 0) {
        outs[i] = ls[0] + ls[1] + ls[2] + ls[3];
        outd[i] = ld[0] + ld[1] + ld[2] + ld[3];
    }
}

// ---------------------------- CSR build (by dst) ----------------------------
__global__ __launch_bounds__(256) void hist_kernel(
    const int* __restrict__ dst, int* __restrict__ cnt, int E, int n)
{
    int t = blockIdx.x * 256 + threadIdx.x;
    if (t >= E + n) return;
    int d = t < E ? dst[t] : (t - E);
    atomicAdd(&cnt[d], 1);
}

// ---- multi-block 3-pass scan ----
__global__ __launch_bounds__(256) void scan1_kernel(
    const int* __restrict__ cnt, int* __restrict__ off,
    int* __restrict__ bsum, int n)
{
    __shared__ int s[256];
    int b = blockIdx.x, t = threadIdx.x, i = b * 256 + t;
    int v = (i < n) ? cnt[i] : 0;
    s[t] = v;
    __syncthreads();
    for (int d = 1; d < 256; d <<= 1) {
        int u = (t >= d) ? s[t - d] : 0;
        __syncthreads();
        s[t] += u;
        __syncthreads();
    }
    if (i < n) off[i] = s[t] - v;     // block-local exclusive
    if (t == 255) bsum[b] = s[255];
}

__global__ __launch_bounds__(256) void scan2_kernel(
    const int* __restrict__ bsum, int* __restrict__ bpre, int nb,
    int* __restrict__ off, int n)
{
    __shared__ int s[256];
    int t = threadIdx.x;
    int v = (t < nb) ? bsum[t] : 0;
    s[t] = v;
    __syncthreads();
    for (int d = 1; d < 256; d <<= 1) {
        int u = (t >= d) ? s[t - d] : 0;
        __syncthreads();
        s[t] += u;
        __syncthreads();
    }
    if (t < nb) bpre[t] = s[t] - v;
    if (t == 255) off[n] = s[255];
}

__global__ __launch_bounds__(256) void scan3_kernel(
    int* __restrict__ off, int* __restrict__ cursor,
    const int* __restrict__ bpre, int n)
{
    int i = blockIdx.x * 256 + threadIdx.x;
    if (i < n) {
        int v = off[i] + bpre[blockIdx.x];
        off[i] = v;
        cursor[i] = v;
    }
}

__global__ __launch_bounds__(256) void scatter_kernel(
    const int* __restrict__ src, const int* __restrict__ dst,
    int* __restrict__ cursor, int* __restrict__ ebuf, int E, int n)
{
    int t = blockIdx.x * 256 + threadIdx.x;
    if (t >= E + n) return;
    int s = t < E ? src[t] : (t - E);
    int d = t < E ? dst[t] : (t - E);
    int pos = atomicAdd(&cursor[d], 1);
    ebuf[pos] = s;
}

// ------------- fused softmax + aggregate, F=256 fixed -----------------------
template<int EPI>
__global__ __launch_bounds__(256) void gat_agg2(
    const int* __restrict__ off, const int* __restrict__ ebuf,
    const float* __restrict__ as_, const float* __restrict__ ad_,
    const float* __restrict__ x, const float* __restrict__ bias,
    const int* __restrict__ dmap,
    float* __restrict__ outF, unsigned short* __restrict__ outH,
    unsigned short* __restrict__ outL)
{
    __shared__ float sacc[4][256];
    __shared__ int   sS[128];
    __shared__ float sE[128];
    __shared__ float sred[8];
    int d = dmap ? dmap[blockIdx.x] : blockIdx.x;
    int tid = threadIdx.x;
    int w = tid >> 6, lane = tid & 63;
    int lo = off[d], hi = off[d + 1], ne = hi - lo;
    float adv = ad_[d];
    const float* xb = x + lane * 4;
    float4 acc0 = {0.f, 0.f, 0.f, 0.f}, acc1 = {0.f, 0.f, 0.f, 0.f};
    float psum = 0.f;

    if (ne <= 128) {
        if (tid < ne) {
            int s = ebuf[lo + tid];
            sS[tid] = s;
            sE[tid] = lrelu(as_[s] + adv);
        }
        __syncthreads();
        float m = (tid < ne) ? sE[tid] : -INFINITY;
#pragma unroll
        for (int o = 32; o; o >>= 1) m = fmaxf(m, __shfl_xor(m, o));
        if (lane == 0) sred[w] = m;
        __syncthreads();
        m = fmaxf(fmaxf(sred[0], sred[1]), fmaxf(sred[2], sred[3]));
        if (tid < ne) sE[tid] = expf(sE[tid] - m);
        __syncthreads();
        int i = w;
        for (; i + 4 < ne; i += 8) {
            int s0 = sS[i], s1 = sS[i + 4];
            float e0 = sE[i], e1 = sE[i + 4];
            float4 v0 = *(const float4*)(xb + (long)s0 * 256);
            float4 v1 = *(const float4*)(xb + (long)s1 * 256);
            psum += e0; psum += e1;
            acc0.x = fmaf(e0, v0.x, acc0.x); acc0.y = fmaf(e0, v0.y, acc0.y);
            acc0.z = fmaf(e0, v0.z, acc0.z); acc0.w = fmaf(e0, v0.w, acc0.w);
            acc1.x = fmaf(e1, v1.x, acc1.x); acc1.y = fmaf(e1, v1.y, acc1.y);
            acc1.z = fmaf(e1, v1.z, acc1.z); acc1.w = fmaf(e1, v1.w, acc1.w);
        }
        if (i < ne) {
            int s0 = sS[i];
            float e0 = sE[i];
            float4 v0 = *(const float4*)(xb + (long)s0 * 256);
            psum += e0;
            acc0.x = fmaf(e0, v0.x, acc0.x); acc0.y = fmaf(e0, v0.y, acc0.y);
            acc0.z = fmaf(e0, v0.z, acc0.z); acc0.w = fmaf(e0, v0.w, acc0.w);
        }
    } else {
        float m = -INFINITY;
        for (int p = lo + tid; p < hi; p += 256)
            m = fmaxf(m, lrelu(as_[ebuf[p]] + adv));
#pragma unroll
        for (int o = 32; o; o >>= 1) m = fmaxf(m, __shfl_xor(m, o));
        if (lane == 0) sred[w] = m;
        __syncthreads();
        m = fmaxf(fmaxf(sred[0], sred[1]), fmaxf(sred[2], sred[3]));
        for (int c = lo; c < hi; c += 128) {
            int cn = min(128, hi - c);
            __syncthreads();
            if (tid < cn) {
                int s = ebuf[c + tid];
                sS[tid] = s;
                sE[tid] = expf(lrelu(as_[s] + adv) - m);
            }
            __syncthreads();
            int i = w;
            for (; i + 4 < cn; i += 8) {
                int s0 = sS[i], s1 = sS[i + 4];
                float e0 = sE[i], e1 = sE[i + 4];
                float4 v0 = *(const float4*)(xb + (long)s0 * 256);
                float4 v1 = *(const float4*)(xb + (long)s1 * 256);
                psum += e0; psum += e1;
                acc0.x = fmaf(e0, v0.x, acc0.x); acc0.y = fmaf(e0, v0.y, acc0.y);
                acc0.z = fmaf(e0, v0.z, acc0.z); acc0.w = fmaf(e0, v0.w, acc0.w);
                acc1.x = fmaf(e1, v1.x, acc1.x); acc1.y = fmaf(e1, v1.y, acc1.y);
                acc1.z = fmaf(e1, v1.z, acc1.z); acc1.w = fmaf(e1, v1.w, acc1.w);
            }
            if (i < cn) {
                int s0 = sS[i];
                float e0 = sE[i];
                float4 v0 = *(const float4*)(xb + (long)s0 * 256);
                psum += e0;
                acc0.x = fmaf(e0, v0.x, acc0.x); acc0.y = fmaf(e0, v0.y, acc0.y);
                acc0.z = fmaf(e0, v0.z, acc0.z); acc0.w = fmaf(e0, v0.w, acc0.w);
            }
        }
    }
    acc0.x += acc1.x; acc0.y += acc1.y; acc0.z += acc1.z; acc0.w += acc1.w;
    if (lane == 0) sred[4 + w] = psum;
    *(float4*)&sacc[w][lane * 4] = acc0;
    __syncthreads();
    float inv = 1.f / (sred[4] + sred[5] + sred[6] + sred[7]);
    float v = (sacc[0][tid] + sacc[1][tid] + sacc[2][tid] + sacc[3][tid]) * inv;
    long o = (long)blockIdx.x * 256 + tid;
    if (EPI == 1) {
        outF[o] = fmaxf(v + bias[tid], 0.f);
    } else {
        unsigned short h = f2bf(v);
        outH[o] = h;
        outL[o] = f2bf(v - bf2f(h));
    }
}

// comb right half: comb[i][256+t] = split(cfin[cidx[i]][t])
__global__ __launch_bounds__(256) void gather_cell_split(
    const float* __restrict__ cfin, const int* __restrict__ cidx,
    unsigned short* __restrict__ combH, unsigned short* __restrict__ combL)
{
    int i = blockIdx.x;
    int t = threadIdx.x;
    float v = cfin[(long)cidx[i] * 256 + t];
    long b = (long)i * 512 + 256 + t;
    unsigned short h = f2bf(v);
    combH[b] = h;
    combL[b] = f2bf(v - bf2f(h));
}

// out[i] = h[i] . w + b[0]
__global__ __launch_bounds__(256) void head_final_kernel(
    const float* __restrict__ h, const float* __restrict__ w,
    const float* __restrict__ b, float* __restrict__ out, int M)
{
    int gw = blockIdx.x * 4 + (threadIdx.x >> 6);
    int lane = threadIdx.x & 63;
    if (gw >= M) return;
    const float* row = h + (long)gw * 512;
    float s = 0.f;
#pragma unroll
    for (int f = lane; f < 512; f += 64) s += row[f] * w[f];
#pragma unroll
    for (int off = 32; off; off >>= 1) s += __shfl_down(s, off);
    if (lane == 0) out[gw] = s + b[0];
}

// ------------------------------ orchestration -------------------------------
// 64-row bands; ny padded to x8 for the XCD swizzle bijection
static inline dim3 mfma_grid64(int M, int N) {
    int ny = (M + 63) / 64;
    ny = (ny + 7) & ~7;
    return dim3(N / 128, ny);
}

extern "C" void kernel_launch(void* const* d_in, const int* in_sizes, int n_in,
                              void* d_out, int out_size, void* d_ws, size_t ws_size,
                              hipStream_t stream)
{
    const float* drug_x = (const float*)d_in[0];
    const float* cell_x = (const float*)d_in[1];
    const int* d_ei = (const int*)d_in[2];
    const int* c_ei = (const int*)d_in[3];
    const int* d_idx = (const int*)d_in[4];
    const int* c_idx = (const int*)d_in[5];
    const float* dW1 = (const float*)d_in[6];
    const float* db1 = (const float*)d_in[7];
    const float* cW1 = (const float*)d_in[8];
    const float* cb1 = (const float*)d_in[9];
    const float* cW2 = (const float*)d_in[10];
    const float* cb2 = (const float*)d_in[11];
    const float* gdW = (const float*)d_in[12];
    const float* gdas = (const float*)d_in[13];
    const float* gdad = (const float*)d_in[14];
    const float* gdb = (const float*)d_in[15];
    const float* g1W = (const float*)d_in[16];
    const float* g1as = (const float*)d_in[17];
    const float* g1ad = (const float*)d_in[18];
    const float* g1b = (const float*)d_in[19];
    const float* g2W = (const float*)d_in[20];
    const float* g2as = (const float*)d_in[21];
    const float* g2ad = (const float*)d_in[22];
    const float* g2b = (const float*)d_in[23];
    const float* rW1 = (const float*)d_in[24];
    const float* rb1 = (const float*)d_in[25];
    const float* rW2 = (const float*)d_in[26];
    const float* rb2 = (const float*)d_in[27];
    const float* rW3 = (const float*)d_in[28];
    const float* rb3 = (const float*)d_in[29];

    const int ND = in_sizes[0] / 128;     // 50000
    const int NC = in_sizes[1] / 735;     // 10000
    const int ED = in_sizes[2] / 2;       // 800000
    const int EC = in_sizes[3] / 2;       // 160000
    const int NB = in_sizes[4];           // 16384

    const int* d_src = d_ei;
    const int* d_dst = d_ei + ED;
    const int* c_src = c_ei;
    const int* c_dst = c_ei + EC;

    const size_t MB = 1ull << 20;
    const size_t KB = 1024;
    char* ws = (char*)d_ws;

    // ---- weight split region [0, 9MB) ----
    size_t wo = 0;
    auto walloc = [&](size_t elems) -> unsigned short* {
        unsigned short* p = (unsigned short*)(ws + wo);
        wo += ((elems * 2 + 255) & ~(size_t)255);
        return p;
    };
    unsigned short* dW1h = walloc(256 * 128);  unsigned short* dW1l = walloc(256 * 128);
    unsigned short* cW1h = walloc(1024 * 736); unsigned short* cW1l = walloc(1024 * 736);
    unsigned short* cW2h = walloc(256 * 1024); unsigned short* cW2l = walloc(256 * 1024);
    unsigned short* gdWh = walloc(256 * 256);  unsigned short* gdWl = walloc(256 * 256);
    unsigned short* g1Wh = walloc(1024 * 256); unsigned short* g1Wl = walloc(1024 * 256);
    unsigned short* g2Wh = walloc(256 * 1024); unsigned short* g2Wl = walloc(256 * 1024);
    unsigned short* rW1h = walloc(512 * 512);  unsigned short* rW1l = walloc(512 * 512);
    unsigned short* rW2h = walloc(512 * 512);  unsigned short* rW2l = walloc(512 * 512);

    // ---- small scratch [9, 16MB) ----
    float* wa_ds  = (float*)(ws + 9 * MB);
    float* wa_dd  = (float*)(ws + 9 * MB + 4 * KB);
    float* wa_c1s = (float*)(ws + 9 * MB + 8 * KB);
    float* wa_c1d = (float*)(ws + 9 * MB + 12 * KB);
    float* cas    = (float*)(ws + 9 * MB + 64 * KB);
    float* cad    = (float*)(ws + 9 * MB + 128 * KB);
    int*   coff   = (int*)(ws + 9 * MB + 192 * KB);
    int*   ccur   = (int*)(ws + 9 * MB + 256 * KB);
    int*   ccnt   = (int*)(ws + 9 * MB + 320 * KB);
    int*   bsum_d = (int*)(ws + 9 * MB + 400 * KB);   // 196 ints
    int*   bpre_d = (int*)(ws + 9 * MB + 404 * KB);
    int*   bsum_c = (int*)(ws + 9 * MB + 408 * KB);   // 40 ints
    int*   bpre_c = (int*)(ws + 9 * MB + 412 * KB);
    int*   cebuf  = (int*)(ws + 10 * MB);              // EC+NC ints
    float* das    = (float*)(ws + 11 * MB);
    float* dad    = (float*)(ws + 11 * MB + 256 * KB);
    int*   doff   = (int*)(ws + 11 * MB + 512 * KB);
    int*   dcur   = (int*)(ws + 11 * MB + 768 * KB);
    int*   dcnt   = (int*)(ws + 12 * MB);
    int*   debuf  = (int*)(ws + 12 * MB + 256 * KB);   // ED+ND ints -> ends ~15.7MB

    // ---- big buffers (liveness-checked) ----
    float* dbuf  = (float*)(ws + 16 * MB);                    // d0 [ND,256] [16,65)
    unsigned short* aggdh = (unsigned short*)(ws + 66 * MB);  // [NB,256] [66,74)
    unsigned short* aggdl = (unsigned short*)(ws + 75 * MB);  // [75,83)
    unsigned short* combh = (unsigned short*)(ws + 84 * MB);  // [NB,512] [84,100)
    unsigned short* combl = (unsigned short*)(ws + 101 * MB); // [101,117)
    unsigned short* c0h = (unsigned short*)(ws + 16 * MB);    // [10112,1024] [16,36)  (dbuf dead)
    unsigned short* c0l = (unsigned short*)(ws + 36 * MB);    // [36,56)
    float* c1b   = (float*)(ws + 118 * MB);                   // [NC,256] [118,128)
    unsigned short* aggch = (unsigned short*)(ws + 129 * MB); // [10112,256] [129,134.1)
    unsigned short* aggcl = (unsigned short*)(ws + 135 * MB); // [135,140.1)
    unsigned short* c2h = (unsigned short*)(ws + 16 * MB);    // [16,36)  (c0 dead)
    unsigned short* c2l = (unsigned short*)(ws + 36 * MB);    // [36,56)
    float* xc2   = (float*)(ws + 118 * MB);                   // [118,128) (c1 dead)
    float* cfin  = (float*)(ws + 141 * MB);                   // [141,151)
    unsigned short* h1h = (unsigned short*)(ws + 16 * MB);    // [NB,512] [16,32) (c2 dead)
    unsigned short* h1l = (unsigned short*)(ws + 33 * MB);    // [33,49)
    float* h2b   = (float*)(ws + 50 * MB);                    // [NB,512] fp32 [50,82)
    // cell_x split planes [NC pad 10112][736]
    unsigned short* cxh = (unsigned short*)(ws + 152 * MB);   // [152,166.9)
    unsigned short* cxl = (unsigned short*)(ws + 167 * MB);   // [167,181.9)

    // ================= fused prepass: 8 splits + 4 matvecs ===================
    SJobs js;
    js.j[0] = {dW1, dW1h, dW1l, 128, 256, 128, 0};
    js.j[1] = {cW1, cW1h, cW1l, 735, 1024, 736, 32};
    js.j[2] = {cW2, cW2h, cW2l, 1024, 256, 1024, 768};
    js.j[3] = {gdW, gdWh, gdWl, 256, 256, 256, 1024};
    js.j[4] = {g1W, g1Wh, g1Wl, 256, 1024, 256, 1088};
    js.j[5] = {g2W, g2Wh, g2Wl, 1024, 256, 1024, 1344};
    js.j[6] = {rW1, rW1h, rW1l, 512, 512, 512, 1600};
    js.j[7] = {rW2, rW2h, rW2l, 512, 512, 512, 1856};
    split_transpose_multi<<<2112, 256, 0, stream>>>(js);
    split_cell_rows<<<NC, 256, 0, stream>>>(cell_x, cxh, cxl, NC);
    matvec4<<<1024, 256, 0, stream>>>(gdW, gdas, gdad, wa_ds, wa_dd,
                                      g1W, g1as, g1ad, wa_c1s, wa_c1d);

    // ======================= drug path (batch-sparse) =======================
    hipMemsetAsync(das, 0, (size_t)ND * 4, stream);
    hipMemsetAsync(dad, 0, (size_t)ND * 4, stream);
    {
        int nblk = 2 * ((ND + 63) / 64);
        gemm_d0_fused<<<nblk, 256, 0, stream>>>(
            drug_x, dW1h, dW1l, db1, wa_ds, wa_dd, dbuf, das, dad, ND, nblk);
    }
    hipMemsetAsync(dcnt, 0, (size_t)ND * 4, stream);
    {
        int tot = ED + ND;
        int nbd = (ND + 255) / 256;
        hist_kernel<<<(tot + 255) / 256, 256, 0, stream>>>(d_dst, dcnt, ED, ND);
        scan1_kernel<<<nbd, 256, 0, stream>>>(dcnt, doff, bsum_d, ND);
        scan2_kernel<<<1, 256, 0, stream>>>(bsum_d, bpre_d, nbd, doff, ND);
        scan3_kernel<<<nbd, 256, 0, stream>>>(doff, dcur, bpre_d, ND);
        scatter_kernel<<<(tot + 255) / 256, 256, 0, stream>>>(d_src, d_dst, dcur, debuf, ED, ND);
        gat_agg2<0><<<NB, 256, 0, stream>>>(doff, debuf, das, dad, dbuf, nullptr,
                                            d_idx, nullptr, aggdh, aggdl);
    }
    // comb left half = relu(aggd_batch @ gdW + gdb) as split planes (stride 512)
    gemm2<1, 1><<<mfma_grid64(NB, 256), 256, 0, stream>>>(
        aggdh, aggdl, gdWh, gdWl, gdb, nullptr, combh, combl,
        NB, 256, 256, 256, 512);

    // ======================= cell path =======================
    gemm2<1, 1><<<mfma_grid64(NC, 1024), 256, 0, stream>>>(
        cxh, cxl, cW1h, cW1l, cb1, nullptr, c0h, c0l,
        NC, 736, 1024, 736, 1024);
    gemm2<1, 0><<<mfma_grid64(NC, 256), 256, 0, stream>>>(
        c0h, c0l, cW2h, cW2l, cb2, c1b, nullptr, nullptr,
        NC, 1024, 256, 1024, 256);
    att_scalars<<<NC, 256, 0, stream>>>(c1b, wa_c1s, wa_c1d, cas, cad, 256);
    hipMemsetAsync(ccnt, 0, (size_t)NC * 4, stream);
    {
        int tot = EC + NC;
        int nbc = (NC + 255) / 256;
        hist_kernel<<<(tot + 255) / 256, 256, 0, stream>>>(c_dst, ccnt, EC, NC);
        scan1_kernel<<<nbc, 256, 0, stream>>>(ccnt, coff, bsum_c, NC);
        scan2_kernel<<<1, 256, 0, stream>>>(bsum_c, bpre_c, nbc, coff, NC);
        scan3_kernel<<<nbc, 256, 0, stream>>>(coff, ccur, bpre_c, NC);
        scatter_kernel<<<(tot + 255) / 256, 256, 0, stream>>>(c_src, c_dst, ccur, cebuf, EC, NC);
        gat_agg2<0><<<NC, 256, 0, stream>>>(coff, cebuf, cas, cad, c1b, nullptr,
                                            nullptr, nullptr, aggch, aggcl);
    }
    gemm2<1, 1><<<mfma_grid64(NC, 1024), 256, 0, stream>>>(
        aggch, aggcl, g1Wh, g1Wl, g1b, nullptr, c2h, c2l,
        NC, 256, 1024, 256, 1024);
    gemm2<0, 0><<<mfma_grid64(NC, 256), 256, 0, stream>>>(
        c2h, c2l, g2Wh, g2Wl, nullptr, xc2, nullptr, nullptr,
        NC, 1024, 256, 1024, 256);
    att_scalars<<<NC, 256, 0, stream>>>(xc2, g2as, g2ad, cas, cad, 256);
    gat_agg2<1><<<NC, 256, 0, stream>>>(coff, cebuf, cas, cad, xc2, g2b,
                                        nullptr, cfin, nullptr, nullptr);

    // ======================= head =======================
    gather_cell_split<<<NB, 256, 0, stream>>>(cfin, c_idx, combh, combl);
    gemm2<2, 1><<<mfma_grid64(NB, 512), 256, 0, stream>>>(
        combh, combl, rW1h, rW1l, rb1, nullptr, h1h, h1l,
        NB, 512, 512, 512, 512);
    gemm2<2, 0><<<mfma_grid64(NB, 512), 256, 0, stream>>>(
        h1h, h1l, rW2h, rW2l, rb2, h2b, nullptr, nullptr,
        NB, 512, 512, 512, 512);
    head_final_kernel<<<(NB + 3) / 4, 256, 0, stream>>>(h2b, rW3, rb3, (float*)d_out, NB);
}

// Round 11
// 747.706 us; speedup vs baseline: 1.0223x; 1.0223x over previous
//
#include <hip/hip_runtime.h>
#include <math.h>

#define NEG_SLOPE 0.2f

typedef __attribute__((ext_vector_type(8))) short short8;
typedef __attribute__((ext_vector_type(4))) float floatx4;

// ---------------- fp32 <-> bf16 split helpers (RNE) ----------------
__device__ __forceinline__ unsigned short f2bf(float f) {
    unsigned u = __float_as_uint(f);
    u += 0x7fffu + ((u >> 16) & 1u);
    return (unsigned short)(u >> 16);
}
__device__ __forceinline__ float bf2f(unsigned short h) {
    return __uint_as_float((unsigned)h << 16);
}
__device__ __forceinline__ float lrelu(float v) {
    return v > 0.f ? v : NEG_SLOPE * v;
}

// ---- async global->LDS, 16B per lane (gfx950). dest = uniform base + lane*16
typedef __attribute__((address_space(3))) unsigned int lds_u32;
typedef const __attribute__((address_space(1))) unsigned int glb_u32c;
__device__ __forceinline__ void gll16(const unsigned short* g, unsigned short* l) {
    __builtin_amdgcn_global_load_lds((glb_u32c*)g, (lds_u32*)l, 16, 0, 0);
}

// ---------------- fused weight pre-pass: 8 jobs in one launch ----------------
struct SJob { const float* W; unsigned short* Th; unsigned short* Tl; int K, N, Kp, base; };
struct SJobs { SJob j[8]; };

__global__ __launch_bounds__(256) void split_transpose_multi(SJobs js) {
    int t = blockIdx.x;
    int ji = 0;
#pragma unroll
    for (int q = 1; q < 8; ++q) if (t >= js.j[q].base) ji = q;
    const SJob jb = js.j[ji];
    int local = t - jb.base;
    int ntiles = jb.N / 32;
    int tn = local % ntiles, tk = local / ntiles;
    int k0 = tk * 32, n0 = tn * 32;
    __shared__ float tbuf[32][33];
    int c = threadIdx.x & 31, r = threadIdx.x >> 5;
    for (int rr = r; rr < 32; rr += 8) {
        int k = k0 + rr, n = n0 + c;
        tbuf[rr][c] = (k < jb.K && n < jb.N) ? jb.W[(long)k * jb.N + n] : 0.f;
    }
    __syncthreads();
    for (int rr = r; rr < 32; rr += 8) {
        int n = n0 + rr, k = k0 + c;
        if (n < jb.N && k < jb.Kp) {
            float v = tbuf[c][rr];
            unsigned short h = f2bf(v);
            jb.Th[(long)n * jb.Kp + k] = h;
            jb.Tl[(long)n * jb.Kp + k] = f2bf(v - bf2f(h));
        }
    }
}

// ---- cell_x row split: [M][735] fp32 -> [M][736] bf16 hi/lo (zero-pad) ----
__global__ __launch_bounds__(256) void split_cell_rows(
    const float* __restrict__ X, unsigned short* __restrict__ H,
    unsigned short* __restrict__ L, int M)
{
    long i = blockIdx.x;
    int t = threadIdx.x;
    const float* r = X + i * 735;
    for (int c = t; c < 736; c += 256) {
        float v = (c < 735) ? r[c] : 0.f;
        unsigned short h = f2bf(v);
        H[i * 736 + c] = h;
        L[i * 736 + c] = f2bf(v - bf2f(h));
    }
}

// ---- 4 fused matvecs: wa[k] = sum_n W[k][n]*a[n] (k in [0,256) each) ----
__global__ __launch_bounds__(256) void matvec4(
    const float* __restrict__ gdW, const float* __restrict__ gdas, const float* __restrict__ gdad,
    float* __restrict__ wds, float* __restrict__ wdd,
    const float* __restrict__ g1W, const float* __restrict__ g1as, const float* __restrict__ g1ad,
    float* __restrict__ w1s, float* __restrict__ w1d)
{
    int b = blockIdx.x;
    int sel = b >> 8, k = b & 255, t = threadIdx.x;
    const float *W, *a; float* o; int N;
    if (sel == 0)      { W = gdW; a = gdas; o = wds; N = 256; }
    else if (sel == 1) { W = gdW; a = gdad; o = wdd; N = 256; }
    else if (sel == 2) { W = g1W; a = g1as; o = w1s; N = 1024; }
    else               { W = g1W; a = g1ad; o = w1d; N = 1024; }
    float s = 0.f;
    for (int n = t; n < N; n += 256) s += W[(long)k * N + n] * a[n];
#pragma unroll
    for (int off = 32; off; off >>= 1) s += __shfl_down(s, off);
    __shared__ float ls[4];
    if ((t & 63) == 0) ls[t >> 6] = s;
    __syncthreads();
    if (t == 0) o[k] = ls[0] + ls[1] + ls[2] + ls[3];
}

// ======== dedicated d0 kernel: M x 128 @ 128 x 256, no LDS, no barriers ======
__global__ __launch_bounds__(256, 3) void gemm_d0_fused(
    const float* __restrict__ A,                    // [M][128] fp32
    const unsigned short* __restrict__ Bh_g,        // [256][128] bf16-hi
    const unsigned short* __restrict__ Bl_g,        // [256][128] bf16-lo
    const float* __restrict__ bias,                 // [256]
    const float* __restrict__ was, const float* __restrict__ wad, // [256]
    float* __restrict__ C,                          // [M][256] fp32 (relu'd)
    float* __restrict__ das, float* __restrict__ dad,
    int M, int nblk)
{
    int bid = blockIdx.x;
    int q = nblk >> 3, rr = nblk & 7;
    int xcd = bid & 7, idx = bid >> 3;
    int wg = (xcd < rr ? xcd * (q + 1) : rr * (q + 1) + (xcd - rr) * q) + idx;
    int rb = wg >> 1, colh = wg & 1;
    int m0 = rb * 64, n0 = colh * 128;
    if (m0 >= M) return;
    const int tid = threadIdx.x;
    const int wave = tid >> 6, lane = tid & 63;
    const int lm = lane & 15, lq = lane >> 4;
    const int wn = n0 + wave * 32;

    floatx4 acc[4][2];
    floatx4 zero = {0.f, 0.f, 0.f, 0.f};
#pragma unroll
    for (int i = 0; i < 4; ++i)
#pragma unroll
        for (int j = 0; j < 2; ++j) acc[i][j] = zero;

#pragma unroll
    for (int ks = 0; ks < 4; ++ks) {
        const int kc = ks * 32 + lq * 8;
        short8 bh[2], bl[2];
#pragma unroll
        for (int j = 0; j < 2; ++j) {
            long bo = (long)(wn + j * 16 + lm) * 128 + kc;
            bh[j] = *(const short8*)(Bh_g + bo);
            bl[j] = *(const short8*)(Bl_g + bo);
        }
        short8 ah[4], al[4];
#pragma unroll
        for (int i = 0; i < 4; ++i) {
            int gm = m0 + i * 16 + lm;
            float4 t0 = {0.f, 0.f, 0.f, 0.f}, t1 = {0.f, 0.f, 0.f, 0.f};
            if (gm < M) {
                const float* ap = A + (long)gm * 128 + kc;
                t0 = *(const float4*)ap;
                t1 = *(const float4*)(ap + 4);
            }
            short8 h, l;
            float f;
            f = t0.x; h[0] = f2bf(f); l[0] = f2bf(f - bf2f(h[0]));
            f = t0.y; h[1] = f2bf(f); l[1] = f2bf(f - bf2f(h[1]));
            f = t0.z; h[2] = f2bf(f); l[2] = f2bf(f - bf2f(h[2]));
            f = t0.w; h[3] = f2bf(f); l[3] = f2bf(f - bf2f(h[3]));
            f = t1.x; h[4] = f2bf(f); l[4] = f2bf(f - bf2f(h[4]));
            f = t1.y; h[5] = f2bf(f); l[5] = f2bf(f - bf2f(h[5]));
            f = t1.z; h[6] = f2bf(f); l[6] = f2bf(f - bf2f(h[6]));
            f = t1.w; h[7] = f2bf(f); l[7] = f2bf(f - bf2f(h[7]));
            ah[i] = h; al[i] = l;
        }
#pragma unroll
        for (int i = 0; i < 4; ++i)
#pragma unroll
            for (int j = 0; j < 2; ++j) {
                acc[i][j] = __builtin_amdgcn_mfma_f32_16x16x32_bf16(ah[i], bh[j], acc[i][j], 0, 0, 0);
                acc[i][j] = __builtin_amdgcn_mfma_f32_16x16x32_bf16(al[i], bh[j], acc[i][j], 0, 0, 0);
                acc[i][j] = __builtin_amdgcn_mfma_f32_16x16x32_bf16(ah[i], bl[j], acc[i][j], 0, 0, 0);
            }
    }

    // ---- epilogue: bias+relu, store C, fused att-scalar partials ----
    __shared__ float sps[64][5], spd[64][5];
    float bv[2], wsv[2], wdv[2];
#pragma unroll
    for (int j = 0; j < 2; ++j) {
        int gn = wn + j * 16 + lm;
        bv[j] = bias[gn];
        wsv[j] = was[gn];
        wdv[j] = wad[gn];
    }
#pragma unroll
    for (int i = 0; i < 4; ++i) {
#pragma unroll
        for (int r = 0; r < 4; ++r) {
            int gm = m0 + i * 16 + lq * 4 + r;
            float vs = 0.f, vd = 0.f;
#pragma unroll
            for (int j = 0; j < 2; ++j) {
                int gn = wn + j * 16 + lm;
                float v = fmaxf(acc[i][j][r] + bv[j], 0.f);
                if (gm < M) C[(long)gm * 256 + gn] = v;
                vs = fmaf(v, wsv[j], vs);
                vd = fmaf(v, wdv[j], vd);
            }
#pragma unroll
            for (int o = 8; o; o >>= 1) {
                vs += __shfl_xor(vs, o);
                vd += __shfl_xor(vd, o);
            }
            if (lm == 0) {
                sps[i * 16 + lq * 4 + r][wave] = vs;
                spd[i * 16 + lq * 4 + r][wave] = vd;
            }
        }
    }
    __syncthreads();
    if (tid < 64) {
        int gm = m0 + tid;
        if (gm < M) {
            float s = sps[tid][0] + sps[tid][1] + sps[tid][2] + sps[tid][3];
            float d2 = spd[tid][0] + spd[tid][1] + spd[tid][2] + spd[tid][3];
            atomicAdd(das + gm, s);
            atomicAdd(dad + gm, d2);
        }
    }
}

// ---------------- GEMM via split-bf16 MFMA ----------------------------------
// r11: REVERT to the r9 structure (best measured: 740 us, cW1 75 us,
// occupancy 41%). r10's counted-vmcnt T4 regressed (VGPR 68 / 48KB LDS ->
// occupancy 25%, net -5%). r8/r9/r10 bracket the m233 2-phase plateau;
// accepting the GEMM at ~600 TF for these small-K shapes.
// 4-wave blocks, 64m x 128n tile, single-buffered 24KB LDS, 6 blocks/CU.
// Swizzle (r5: measured 0 conflicts):
//   stage: lane l sources col-slot (l&3)^((l>>3)&3) of row chunk+(l>>2)
//   read:  logical slot lq of row r lives at LDS slot lq^((r>>1)&3)
template<int ACT, int OSPLIT>  // ACT: 0=none,1=relu,2=elu
__global__ __launch_bounds__(256, 6) void gemm2(
    const unsigned short* __restrict__ Ah_g, const unsigned short* __restrict__ Al_g,
    const unsigned short* __restrict__ Bh_g, const unsigned short* __restrict__ Bl_g,
    const float* __restrict__ bias,
    float* __restrict__ C, unsigned short* __restrict__ Ch_g, unsigned short* __restrict__ Cl_g,
    int M, int K, int N, int Kp, int Cs)
{
    __shared__ unsigned short Ah[2048];   // [64 rows][32 k]
    __shared__ unsigned short Al[2048];
    __shared__ unsigned short Bh[4096];   // [128 rows][32 k]
    __shared__ unsigned short Bl[4096];
    const int tid = threadIdx.x;
    const int wave = tid >> 6, lane = tid & 63;
    const int lm = lane & 15, lq = lane >> 4;
    const int wn = wave * 32;            // n-quarter within 128-col tile
    // ---- XCD swizzle (bijective over padded grid) ----
    const int nx = gridDim.x;
    const int lin = blockIdx.y * nx + blockIdx.x;
    const int sup = lin / (8 * nx);
    const int wit = lin - sup * 8 * nx;
    const int rowb = sup * 8 + (wit & 7);
    const int nb = wit >> 3;
    const int m0 = rowb * 64, n0 = nb * 128;
    if (m0 >= M) return;   // padded row-band

    floatx4 acc[4][2];
    floatx4 zero = {0.f, 0.f, 0.f, 0.f};
#pragma unroll
    for (int i = 0; i < 4; ++i)
#pragma unroll
        for (int j = 0; j < 2; ++j) acc[i][j] = zero;

    // ---- staging addresses (per-lane source, wave-uniform LDS chunk) ----
    const int srow = lane >> 2;                       // row within 16-row chunk
    const int sslot = (lane & 3) ^ ((lane >> 3) & 3); // pre-swizzled source slot
    const unsigned short* agh = Ah_g + (long)(m0 + wave * 16 + srow) * Kp + sslot * 8;
    const unsigned short* agl = Al_g + (long)(m0 + wave * 16 + srow) * Kp + sslot * 8;
    const unsigned short* bgh0 = Bh_g + (long)(n0 + wave * 32 + srow) * Kp + sslot * 8;
    const unsigned short* bgh1 = Bh_g + (long)(n0 + wave * 32 + 16 + srow) * Kp + sslot * 8;
    const unsigned short* bgl0 = Bl_g + (long)(n0 + wave * 32 + srow) * Kp + sslot * 8;
    const unsigned short* bgl1 = Bl_g + (long)(n0 + wave * 32 + 16 + srow) * Kp + sslot * 8;
    unsigned short* lAh = &Ah[wave * 512];
    unsigned short* lAl = &Al[wave * 512];
    unsigned short* lBh0 = &Bh[wave * 1024];
    unsigned short* lBh1 = &Bh[wave * 1024 + 512];
    unsigned short* lBl0 = &Bl[wave * 1024];
    unsigned short* lBl1 = &Bl[wave * 1024 + 512];
    const int xa = (lm >> 1) & 3;                     // read-side swizzle key

    for (int k0 = 0; k0 < K; k0 += 32) {
        gll16(agh + k0, lAh);
        gll16(agl + k0, lAl);
        gll16(bgh0 + k0, lBh0);
        gll16(bgh1 + k0, lBh1);
        gll16(bgl0 + k0, lBl0);
        gll16(bgl1 + k0, lBl1);
        __syncthreads();
        short8 fah[4], fal[4], fbh[2], fbl[2];
#pragma unroll
        for (int i = 0; i < 4; ++i) {
            int off = (i * 16 + lm) * 32 + ((lq ^ xa) << 3);
            fah[i] = *(const short8*)&Ah[off];
            fal[i] = *(const short8*)&Al[off];
        }
#pragma unroll
        for (int j = 0; j < 2; ++j) {
            int off = (wn + j * 16 + lm) * 32 + ((lq ^ xa) << 3);
            fbh[j] = *(const short8*)&Bh[off];
            fbl[j] = *(const short8*)&Bl[off];
        }
#pragma unroll
        for (int i = 0; i < 4; ++i)
#pragma unroll
            for (int j = 0; j < 2; ++j) {
                acc[i][j] = __builtin_amdgcn_mfma_f32_16x16x32_bf16(fah[i], fbh[j], acc[i][j], 0, 0, 0);
                acc[i][j] = __builtin_amdgcn_mfma_f32_16x16x32_bf16(fal[i], fbh[j], acc[i][j], 0, 0, 0);
                acc[i][j] = __builtin_amdgcn_mfma_f32_16x16x32_bf16(fah[i], fbl[j], acc[i][j], 0, 0, 0);
            }
        __syncthreads();
    }
    // ---- epilogue: C/D layout col=lane&15, row=quad*4+reg (m89-verified) ----
#pragma unroll
    for (int j = 0; j < 2; ++j) {
        int gn = n0 + wn + j * 16 + lm;
        float bv = bias ? bias[gn] : 0.f;
#pragma unroll
        for (int i = 0; i < 4; ++i) {
#pragma unroll
            for (int r = 0; r < 4; ++r) {
                int gm = m0 + i * 16 + lq * 4 + r;
                if (gm < M) {
                    float v = acc[i][j][r] + bv;
                    if (ACT == 1) v = fmaxf(v, 0.f);
                    if (ACT == 2) v = v > 0.f ? v : expm1f(v);
                    if (OSPLIT) {
                        long o = (long)gm * Cs + gn;
                        unsigned short h = f2bf(v);
                        Ch_g[o] = h;
                        Cl_g[o] = f2bf(v - bf2f(h));
                    } else {
                        C[(long)gm * (long)Cs + gn] = v;
                    }
                }
            }
        }
    }
}

// ---------------- per-node attention scalars (F=256) ----------------
__global__ __launch_bounds__(256) void att_scalars(
    const float* __restrict__ x, const float* __restrict__ avs,
    const float* __restrict__ avd, float* __restrict__ outs,
    float* __restrict__ outd, int F)
{
    const int i = blockIdx.x;
    const int t = threadIdx.x;
    float ps = 0.f, pd = 0.f;
    for (int f = t; f < F; f += 256) {
        float v = x[(long)i * F + f];
        ps += v * avs[f];
        pd += v * avd[f];
    }
#pragma unroll
    for (int off = 32; off; off >>= 1) {
        ps += __shfl_down(ps, off);
        pd += __shfl_down(pd, off);
    }
    __shared__ float ls[4], ld[4];
    int lane = t & 63, w = t >> 6;
    if (lane == 0) { ls[w] = ps; ld[w] = pd; }
    __syncthreads();
    if (t == 0) {
        outs[i] = ls[0] + ls[1] + ls[2] + ls[3];
        outd[i] = ld[0] + ld[1] + ld[2] + ld[3];
    }
}

// ---------------------------- CSR build (by dst) ----------------------------
__global__ __launch_bounds__(256) void hist_kernel(
    const int* __restrict__ dst, int* __restrict__ cnt, int E, int n)
{
    int t = blockIdx.x * 256 + threadIdx.x;
    if (t >= E + n) return;
    int d = t < E ? dst[t] : (t - E);
    atomicAdd(&cnt[d], 1);
}

// ---- multi-block 3-pass scan ----
__global__ __launch_bounds__(256) void scan1_kernel(
    const int* __restrict__ cnt, int* __restrict__ off,
    int* __restrict__ bsum, int n)
{
    __shared__ int s[256];
    int b = blockIdx.x, t = threadIdx.x, i = b * 256 + t;
    int v = (i < n) ? cnt[i] : 0;
    s[t] = v;
    __syncthreads();
    for (int d = 1; d < 256; d <<= 1) {
        int u = (t >= d) ? s[t - d] : 0;
        __syncthreads();
        s[t] += u;
        __syncthreads();
    }
    if (i < n) off[i] = s[t] - v;     // block-local exclusive
    if (t == 255) bsum[b] = s[255];
}

__global__ __launch_bounds__(256) void scan2_kernel(
    const int* __restrict__ bsum, int* __restrict__ bpre, int nb,
    int* __restrict__ off, int n)
{
    __shared__ int s[256];
    int t = threadIdx.x;
    int v = (t < nb) ? bsum[t] : 0;
    s[t] = v;
    __syncthreads();
    for (int d = 1; d < 256; d <<= 1) {
        int u = (t >= d) ? s[t - d] : 0;
        __syncthreads();
        s[t] += u;
        __syncthreads();
    }
    if (t < nb) bpre[t] = s[t] - v;
    if (t == 255) off[n] = s[255];
}

__global__ __launch_bounds__(256) void scan3_kernel(
    int* __restrict__ off, int* __restrict__ cursor,
    const int* __restrict__ bpre, int n)
{
    int i = blockIdx.x * 256 + threadIdx.x;
    if (i < n) {
        int v = off[i] + bpre[blockIdx.x];
        off[i] = v;
        cursor[i] = v;
    }
}

__global__ __launch_bounds__(256) void scatter_kernel(
    const int* __restrict__ src, const int* __restrict__ dst,
    int* __restrict__ cursor, int* __restrict__ ebuf, int E, int n)
{
    int t = blockIdx.x * 256 + threadIdx.x;
    if (t >= E + n) return;
    int s = t < E ? src[t] : (t - E);
    int d = t < E ? dst[t] : (t - E);
    int pos = atomicAdd(&cursor[d], 1);
    ebuf[pos] = s;
}

// ------------- fused softmax + aggregate, one WAVE per output row -----------
// r11: gat_agg2 used a 256-thread block + ~8 barriers + LDS merge per row,
// for rows of avg degree ~17 -> block-overhead dominated. Here one wave owns
// one row: edge-parallel max/exp (lane p covers edge lo+lane+64k), shfl-xor
// reductions, then serial accumulation with __shfl broadcast of (s_i, e_i);
// each lane owns 4 features (lane*4..+3) so a float4 gather per edge.
// Zero barriers, zero LDS, 4 independent rows per block.
// EPI 0: bf16 hi/lo split planes. EPI 1: fp32 bias+relu.
template<int EPI>
__global__ __launch_bounds__(256) void gat_agg3(
    const int* __restrict__ off, const int* __restrict__ ebuf,
    const float* __restrict__ as_, const float* __restrict__ ad_,
    const float* __restrict__ x, const float* __restrict__ bias,
    const int* __restrict__ dmap,
    float* __restrict__ outF, unsigned short* __restrict__ outH,
    unsigned short* __restrict__ outL, int nrows)
{
    int row = blockIdx.x * 4 + (threadIdx.x >> 6);
    int lane = threadIdx.x & 63;
    if (row >= nrows) return;
    int d = dmap ? dmap[row] : row;
    int lo = off[d], hi = off[d + 1];
    float adv = ad_[d];

    // pass 1: global max over edges (lane-strided, ne >= 1 via self-loop)
    float m = -INFINITY;
    for (int p = lo + lane; p < hi; p += 64)
        m = fmaxf(m, lrelu(as_[ebuf[p]] + adv));
#pragma unroll
    for (int o = 32; o; o >>= 1) m = fmaxf(m, __shfl_xor(m, o));

    // pass 2: chunk of 64 edges: lane computes its edge's (s, e), then all
    // lanes sweep the chunk with shfl broadcast, each owning 4 features.
    const float* xb = x + lane * 4;
    float4 acc = {0.f, 0.f, 0.f, 0.f};
    float psum = 0.f;
    for (int base = lo; base < hi; base += 64) {
        int cnt = min(64, hi - base);
        int s = 0;
        float ex = 0.f;
        if (lane < cnt) {
            s = ebuf[base + lane];
            ex = expf(lrelu(as_[s] + adv) - m);
        }
        psum += ex;
        for (int i = 0; i < cnt; ++i) {
            int si = __shfl(s, i);
            float ei = __shfl(ex, i);
            float4 v = *(const float4*)(xb + (long)si * 256);
            acc.x = fmaf(ei, v.x, acc.x);
            acc.y = fmaf(ei, v.y, acc.y);
            acc.z = fmaf(ei, v.z, acc.z);
            acc.w = fmaf(ei, v.w, acc.w);
        }
    }
#pragma unroll
    for (int o = 32; o; o >>= 1) psum += __shfl_xor(psum, o);
    float inv = 1.f / psum;

    long ob = (long)row * 256 + lane * 4;
    if (EPI == 1) {
        float r0 = fmaxf(acc.x * inv + bias[lane * 4 + 0], 0.f);
        float r1 = fmaxf(acc.y * inv + bias[lane * 4 + 1], 0.f);
        float r2 = fmaxf(acc.z * inv + bias[lane * 4 + 2], 0.f);
        float r3 = fmaxf(acc.w * inv + bias[lane * 4 + 3], 0.f);
        float4 r = {r0, r1, r2, r3};
        *(float4*)(outF + ob) = r;
    } else {
        float vv[4] = {acc.x * inv, acc.y * inv, acc.z * inv, acc.w * inv};
#pragma unroll
        for (int j = 0; j < 4; ++j) {
            unsigned short h = f2bf(vv[j]);
            outH[ob + j] = h;
            outL[ob + j] = f2bf(vv[j] - bf2f(h));
        }
    }
}

// comb right half: comb[i][256+t] = split(cfin[cidx[i]][t])
__global__ __launch_bounds__(256) void gather_cell_split(
    const float* __restrict__ cfin, const int* __restrict__ cidx,
    unsigned short* __restrict__ combH, unsigned short* __restrict__ combL)
{
    int i = blockIdx.x;
    int t = threadIdx.x;
    float v = cfin[(long)cidx[i] * 256 + t];
    long b = (long)i * 512 + 256 + t;
    unsigned short h = f2bf(v);
    combH[b] = h;
    combL[b] = f2bf(v - bf2f(h));
}

// out[i] = h[i] . w + b[0]
__global__ __launch_bounds__(256) void head_final_kernel(
    const float* __restrict__ h, const float* __restrict__ w,
    const float* __restrict__ b, float* __restrict__ out, int M)
{
    int gw = blockIdx.x * 4 + (threadIdx.x >> 6);
    int lane = threadIdx.x & 63;
    if (gw >= M) return;
    const float* row = h + (long)gw * 512;
    float s = 0.f;
#pragma unroll
    for (int f = lane; f < 512; f += 64) s += row[f] * w[f];
#pragma unroll
    for (int off = 32; off; off >>= 1) s += __shfl_down(s, off);
    if (lane == 0) out[gw] = s + b[0];
}

// ------------------------------ orchestration -------------------------------
// 64-row bands; ny padded to x8 for the XCD swizzle bijection
static inline dim3 mfma_grid64(int M, int N) {
    int ny = (M + 63) / 64;
    ny = (ny + 7) & ~7;
    return dim3(N / 128, ny);
}

extern "C" void kernel_launch(void* const* d_in, const int* in_sizes, int n_in,
                              void* d_out, int out_size, void* d_ws, size_t ws_size,
                              hipStream_t stream)
{
    const float* drug_x = (const float*)d_in[0];
    const float* cell_x = (const float*)d_in[1];
    const int* d_ei = (const int*)d_in[2];
    const int* c_ei = (const int*)d_in[3];
    const int* d_idx = (const int*)d_in[4];
    const int* c_idx = (const int*)d_in[5];
    const float* dW1 = (const float*)d_in[6];
    const float* db1 = (const float*)d_in[7];
    const float* cW1 = (const float*)d_in[8];
    const float* cb1 = (const float*)d_in[9];
    const float* cW2 = (const float*)d_in[10];
    const float* cb2 = (const float*)d_in[11];
    const float* gdW = (const float*)d_in[12];
    const float* gdas = (const float*)d_in[13];
    const float* gdad = (const float*)d_in[14];
    const float* gdb = (const float*)d_in[15];
    const float* g1W = (const float*)d_in[16];
    const float* g1as = (const float*)d_in[17];
    const float* g1ad = (const float*)d_in[18];
    const float* g1b = (const float*)d_in[19];
    const float* g2W = (const float*)d_in[20];
    const float* g2as = (const float*)d_in[21];
    const float* g2ad = (const float*)d_in[22];
    const float* g2b = (const float*)d_in[23];
    const float* rW1 = (const float*)d_in[24];
    const float* rb1 = (const float*)d_in[25];
    const float* rW2 = (const float*)d_in[26];
    const float* rb2 = (const float*)d_in[27];
    const float* rW3 = (const float*)d_in[28];
    const float* rb3 = (const float*)d_in[29];

    const int ND = in_sizes[0] / 128;     // 50000
    const int NC = in_sizes[1] / 735;     // 10000
    const int ED = in_sizes[2] / 2;       // 800000
    const int EC = in_sizes[3] / 2;       // 160000
    const int NB = in_sizes[4];           // 16384

    const int* d_src = d_ei;
    const int* d_dst = d_ei + ED;
    const int* c_src = c_ei;
    const int* c_dst = c_ei + EC;

    const size_t MB = 1ull << 20;
    const size_t KB = 1024;
    char* ws = (char*)d_ws;

    // ---- weight split region [0, 9MB) ----
    size_t wo = 0;
    auto walloc = [&](size_t elems) -> unsigned short* {
        unsigned short* p = (unsigned short*)(ws + wo);
        wo += ((elems * 2 + 255) & ~(size_t)255);
        return p;
    };
    unsigned short* dW1h = walloc(256 * 128);  unsigned short* dW1l = walloc(256 * 128);
    unsigned short* cW1h = walloc(1024 * 736); unsigned short* cW1l = walloc(1024 * 736);
    unsigned short* cW2h = walloc(256 * 1024); unsigned short* cW2l = walloc(256 * 1024);
    unsigned short* gdWh = walloc(256 * 256);  unsigned short* gdWl = walloc(256 * 256);
    unsigned short* g1Wh = walloc(1024 * 256); unsigned short* g1Wl = walloc(1024 * 256);
    unsigned short* g2Wh = walloc(256 * 1024); unsigned short* g2Wl = walloc(256 * 1024);
    unsigned short* rW1h = walloc(512 * 512);  unsigned short* rW1l = walloc(512 * 512);
    unsigned short* rW2h = walloc(512 * 512);  unsigned short* rW2l = walloc(512 * 512);

    // ---- small scratch [9, 16MB) ----
    float* wa_ds  = (float*)(ws + 9 * MB);
    float* wa_dd  = (float*)(ws + 9 * MB + 4 * KB);
    float* wa_c1s = (float*)(ws + 9 * MB + 8 * KB);
    float* wa_c1d = (float*)(ws + 9 * MB + 12 * KB);
    float* cas    = (float*)(ws + 9 * MB + 64 * KB);
    float* cad    = (float*)(ws + 9 * MB + 128 * KB);
    int*   coff   = (int*)(ws + 9 * MB + 192 * KB);
    int*   ccur   = (int*)(ws + 9 * MB + 256 * KB);
    int*   ccnt   = (int*)(ws + 9 * MB + 320 * KB);
    int*   bsum_d = (int*)(ws + 9 * MB + 400 * KB);   // 196 ints
    int*   bpre_d = (int*)(ws + 9 * MB + 404 * KB);
    int*   bsum_c = (int*)(ws + 9 * MB + 408 * KB);   // 40 ints
    int*   bpre_c = (int*)(ws + 9 * MB + 412 * KB);
    int*   cebuf  = (int*)(ws + 10 * MB);              // EC+NC ints
    float* das    = (float*)(ws + 11 * MB);
    float* dad    = (float*)(ws + 11 * MB + 256 * KB);
    int*   doff   = (int*)(ws + 11 * MB + 512 * KB);
    int*   dcur   = (int*)(ws + 11 * MB + 768 * KB);
    int*   dcnt   = (int*)(ws + 12 * MB);
    int*   debuf  = (int*)(ws + 12 * MB + 256 * KB);   // ED+ND ints -> ends ~15.7MB

    // ---- big buffers (liveness-checked) ----
    float* dbuf  = (float*)(ws + 16 * MB);                    // d0 [ND,256] [16,65)
    unsigned short* aggdh = (unsigned short*)(ws + 66 * MB);  // [NB,256] [66,74)
    unsigned short* aggdl = (unsigned short*)(ws + 75 * MB);  // [75,83)
    unsigned short* combh = (unsigned short*)(ws + 84 * MB);  // [NB,512] [84,100)
    unsigned short* combl = (unsigned short*)(ws + 101 * MB); // [101,117)
    unsigned short* c0h = (unsigned short*)(ws + 16 * MB);    // [10112,1024] [16,36)  (dbuf dead)
    unsigned short* c0l = (unsigned short*)(ws + 36 * MB);    // [36,56)
    float* c1b   = (float*)(ws + 118 * MB);                   // [NC,256] [118,128)
    unsigned short* aggch = (unsigned short*)(ws + 129 * MB); // [10112,256] [129,134.1)
    unsigned short* aggcl = (unsigned short*)(ws + 135 * MB); // [135,140.1)
    unsigned short* c2h = (unsigned short*)(ws + 16 * MB);    // [16,36)  (c0 dead)
    unsigned short* c2l = (unsigned short*)(ws + 36 * MB);    // [36,56)
    float* xc2   = (float*)(ws + 118 * MB);                   // [118,128) (c1 dead)
    float* cfin  = (float*)(ws + 141 * MB);                   // [141,151)
    unsigned short* h1h = (unsigned short*)(ws + 16 * MB);    // [NB,512] [16,32) (c2 dead)
    unsigned short* h1l = (unsigned short*)(ws + 33 * MB);    // [33,49)
    float* h2b   = (float*)(ws + 50 * MB);                    // [NB,512] fp32 [50,82)
    // cell_x split planes [NC pad 10112][736]
    unsigned short* cxh = (unsigned short*)(ws + 152 * MB);   // [152,166.9)
    unsigned short* cxl = (unsigned short*)(ws + 167 * MB);   // [167,181.9)

    // ================= fused prepass: 8 splits + 4 matvecs ===================
    SJobs js;
    js.j[0] = {dW1, dW1h, dW1l, 128, 256, 128, 0};
    js.j[1] = {cW1, cW1h, cW1l, 735, 1024, 736, 32};
    js.j[2] = {cW2, cW2h, cW2l, 1024, 256, 1024, 768};
    js.j[3] = {gdW, gdWh, gdWl, 256, 256, 256, 1024};
    js.j[4] = {g1W, g1Wh, g1Wl, 256, 1024, 256, 1088};
    js.j[5] = {g2W, g2Wh, g2Wl, 1024, 256, 1024, 1344};
    js.j[6] = {rW1, rW1h, rW1l, 512, 512, 512, 1600};
    js.j[7] = {rW2, rW2h, rW2l, 512, 512, 512, 1856};
    split_transpose_multi<<<2112, 256, 0, stream>>>(js);
    split_cell_rows<<<NC, 256, 0, stream>>>(cell_x, cxh, cxl, NC);
    matvec4<<<1024, 256, 0, stream>>>(gdW, gdas, gdad, wa_ds, wa_dd,
                                      g1W, g1as, g1ad, wa_c1s, wa_c1d);

    // ======================= drug path (batch-sparse) =======================
    hipMemsetAsync(das, 0, (size_t)ND * 4, stream);
    hipMemsetAsync(dad, 0, (size_t)ND * 4, stream);
    {
        int nblk = 2 * ((ND + 63) / 64);
        gemm_d0_fused<<<nblk, 256, 0, stream>>>(
            drug_x, dW1h, dW1l, db1, wa_ds, wa_dd, dbuf, das, dad, ND, nblk);
    }
    hipMemsetAsync(dcnt, 0, (size_t)ND * 4, stream);
    {
        int tot = ED + ND;
        int nbd = (ND + 255) / 256;
        hist_kernel<<<(tot + 255) / 256, 256, 0, stream>>>(d_dst, dcnt, ED, ND);
        scan1_kernel<<<nbd, 256, 0, stream>>>(dcnt, doff, bsum_d, ND);
        scan2_kernel<<<1, 256, 0, stream>>>(bsum_d, bpre_d, nbd, doff, ND);
        scan3_kernel<<<nbd, 256, 0, stream>>>(doff, dcur, bpre_d, ND);
        scatter_kernel<<<(tot + 255) / 256, 256, 0, stream>>>(d_src, d_dst, dcur, debuf, ED, ND);
        gat_agg3<0><<<(NB + 3) / 4, 256, 0, stream>>>(doff, debuf, das, dad, dbuf, nullptr,
                                                      d_idx, nullptr, aggdh, aggdl, NB);
    }
    // comb left half = relu(aggd_batch @ gdW + gdb) as split planes (stride 512)
    gemm2<1, 1><<<mfma_grid64(NB, 256), 256, 0, stream>>>(
        aggdh, aggdl, gdWh, gdWl, gdb, nullptr, combh, combl,
        NB, 256, 256, 256, 512);

    // ======================= cell path =======================
    gemm2<1, 1><<<mfma_grid64(NC, 1024), 256, 0, stream>>>(
        cxh, cxl, cW1h, cW1l, cb1, nullptr, c0h, c0l,
        NC, 736, 1024, 736, 1024);
    gemm2<1, 0><<<mfma_grid64(NC, 256), 256, 0, stream>>>(
        c0h, c0l, cW2h, cW2l, cb2, c1b, nullptr, nullptr,
        NC, 1024, 256, 1024, 256);
    att_scalars<<<NC, 256, 0, stream>>>(c1b, wa_c1s, wa_c1d, cas, cad, 256);
    hipMemsetAsync(ccnt, 0, (size_t)NC * 4, stream);
    {
        int tot = EC + NC;
        int nbc = (NC + 255) / 256;
        hist_kernel<<<(tot + 255) / 256, 256, 0, stream>>>(c_dst, ccnt, EC, NC);
        scan1_kernel<<<nbc, 256, 0, stream>>>(ccnt, coff, bsum_c, NC);
        scan2_kernel<<<1, 256, 0, stream>>>(bsum_c, bpre_c, nbc, coff, NC);
        scan3_kernel<<<nbc, 256, 0, stream>>>(coff, ccur, bpre_c, NC);
        scatter_kernel<<<(tot + 255) / 256, 256, 0, stream>>>(c_src, c_dst, ccur, cebuf, EC, NC);
        gat_agg3<0><<<(NC + 3) / 4, 256, 0, stream>>>(coff, cebuf, cas, cad, c1b, nullptr,
                                                      nullptr, nullptr, aggch, aggcl, NC);
    }
    gemm2<1, 1><<<mfma_grid64(NC, 1024), 256, 0, stream>>>(
        aggch, aggcl, g1Wh, g1Wl, g1b, nullptr, c2h, c2l,
        NC, 256, 1024, 256, 1024);
    gemm2<0, 0><<<mfma_grid64(NC, 256), 256, 0, stream>>>(
        c2h, c2l, g2Wh, g2Wl, nullptr, xc2, nullptr, nullptr,
        NC, 1024, 256, 1024, 256);
    att_scalars<<<NC, 256, 0, stream>>>(xc2, g2as, g2ad, cas, cad, 256);
    gat_agg3<1><<<(NC + 3) / 4, 256, 0, stream>>>(coff, cebuf, cas, cad, xc2, g2b,
                                                  nullptr, cfin, nullptr, nullptr, NC);

    // ======================= head =======================
    gather_cell_split<<<NB, 256, 0, stream>>>(cfin, c_idx, combh, combl);
    gemm2<2, 1><<<mfma_grid64(NB, 512), 256, 0, stream>>>(
        combh, combl, rW1h, rW1l, rb1, nullptr, h1h, h1l,
        NB, 512, 512, 512, 512);
    gemm2<2, 0><<<mfma_grid64(NB, 512), 256, 0, stream>>>(
        h1h, h1l, rW2h, rW2l, rb2, h2b, nullptr, nullptr,
        NB, 512, 512, 512, 512);
    head_final_kernel<<<(NB + 3) / 4, 256, 0, stream>>>(h2b, rW3, rb3, (float*)d_out, NB);
}

// Round 12
// 688.800 us; speedup vs baseline: 1.1097x; 1.0855x over previous
//
#include <hip/hip_runtime.h>
#include <math.h>

#define NEG_SLOPE 0.2f

typedef __attribute__((ext_vector_type(8))) short short8;
typedef __attribute__((ext_vector_type(4))) float floatx4;

// ---------------- fp32 <-> bf16 split helpers (RNE) ----------------
__device__ __forceinline__ unsigned short f2bf(float f) {
    unsigned u = __float_as_uint(f);
    u += 0x7fffu + ((u >> 16) & 1u);
    return (unsigned short)(u >> 16);
}
__device__ __forceinline__ float bf2f(unsigned short h) {
    return __uint_as_float((unsigned)h << 16);
}
__device__ __forceinline__ float lrelu(float v) {
    return v > 0.f ? v : NEG_SLOPE * v;
}

// ---- async global->LDS, 16B per lane (gfx950). dest = uniform base + lane*16
typedef __attribute__((address_space(3))) unsigned int lds_u32;
typedef const __attribute__((address_space(1))) unsigned int glb_u32c;
__device__ __forceinline__ void gll16(const unsigned short* g, unsigned short* l) {
    __builtin_amdgcn_global_load_lds((glb_u32c*)g, (lds_u32*)l, 16, 0, 0);
}

// ---------------- fused weight pre-pass: 8 jobs in one launch ----------------
struct SJob { const float* W; unsigned short* Th; unsigned short* Tl; int K, N, Kp, base; };
struct SJobs { SJob j[8]; };

__global__ __launch_bounds__(256) void split_transpose_multi(SJobs js) {
    int t = blockIdx.x;
    int ji = 0;
#pragma unroll
    for (int q = 1; q < 8; ++q) if (t >= js.j[q].base) ji = q;
    const SJob jb = js.j[ji];
    int local = t - jb.base;
    int ntiles = jb.N / 32;
    int tn = local % ntiles, tk = local / ntiles;
    int k0 = tk * 32, n0 = tn * 32;
    __shared__ float tbuf[32][33];
    int c = threadIdx.x & 31, r = threadIdx.x >> 5;
    for (int rr = r; rr < 32; rr += 8) {
        int k = k0 + rr, n = n0 + c;
        tbuf[rr][c] = (k < jb.K && n < jb.N) ? jb.W[(long)k * jb.N + n] : 0.f;
    }
    __syncthreads();
    for (int rr = r; rr < 32; rr += 8) {
        int n = n0 + rr, k = k0 + c;
        if (n < jb.N && k < jb.Kp) {
            float v = tbuf[c][rr];
            unsigned short h = f2bf(v);
            jb.Th[(long)n * jb.Kp + k] = h;
            jb.Tl[(long)n * jb.Kp + k] = f2bf(v - bf2f(h));
        }
    }
}

// ---- cell_x row split: [M][735] fp32 -> [M][736] bf16 hi/lo (zero-pad) ----
__global__ __launch_bounds__(256) void split_cell_rows(
    const float* __restrict__ X, unsigned short* __restrict__ H,
    unsigned short* __restrict__ L, int M)
{
    long i = blockIdx.x;
    int t = threadIdx.x;
    const float* r = X + i * 735;
    for (int c = t; c < 736; c += 256) {
        float v = (c < 735) ? r[c] : 0.f;
        unsigned short h = f2bf(v);
        H[i * 736 + c] = h;
        L[i * 736 + c] = f2bf(v - bf2f(h));
    }
}

// ---- 4 fused matvecs: wa[k] = sum_n W[k][n]*a[n] (k in [0,256) each) ----
__global__ __launch_bounds__(256) void matvec4(
    const float* __restrict__ gdW, const float* __restrict__ gdas, const float* __restrict__ gdad,
    float* __restrict__ wds, float* __restrict__ wdd,
    const float* __restrict__ g1W, const float* __restrict__ g1as, const float* __restrict__ g1ad,
    float* __restrict__ w1s, float* __restrict__ w1d)
{
    int b = blockIdx.x;
    int sel = b >> 8, k = b & 255, t = threadIdx.x;
    const float *W, *a; float* o; int N;
    if (sel == 0)      { W = gdW; a = gdas; o = wds; N = 256; }
    else if (sel == 1) { W = gdW; a = gdad; o = wdd; N = 256; }
    else if (sel == 2) { W = g1W; a = g1as; o = w1s; N = 1024; }
    else               { W = g1W; a = g1ad; o = w1d; N = 1024; }
    float s = 0.f;
    for (int n = t; n < N; n += 256) s += W[(long)k * N + n] * a[n];
#pragma unroll
    for (int off = 32; off; off >>= 1) s += __shfl_down(s, off);
    __shared__ float ls[4];
    if ((t & 63) == 0) ls[t >> 6] = s;
    __syncthreads();
    if (t == 0) o[k] = ls[0] + ls[1] + ls[2] + ls[3];
}

// ======== dedicated d0 kernel: M x 128 @ 128 x 256, no LDS, no barriers ======
__global__ __launch_bounds__(256, 3) void gemm_d0_fused(
    const float* __restrict__ A,
    const unsigned short* __restrict__ Bh_g,
    const unsigned short* __restrict__ Bl_g,
    const float* __restrict__ bias,
    const float* __restrict__ was, const float* __restrict__ wad,
    float* __restrict__ C,
    float* __restrict__ das, float* __restrict__ dad,
    int M, int nblk)
{
    int bid = blockIdx.x;
    int q = nblk >> 3, rr = nblk & 7;
    int xcd = bid & 7, idx = bid >> 3;
    int wg = (xcd < rr ? xcd * (q + 1) : rr * (q + 1) + (xcd - rr) * q) + idx;
    int rb = wg >> 1, colh = wg & 1;
    int m0 = rb * 64, n0 = colh * 128;
    if (m0 >= M) return;
    const int tid = threadIdx.x;
    const int wave = tid >> 6, lane = tid & 63;
    const int lm = lane & 15, lq = lane >> 4;
    const int wn = n0 + wave * 32;

    floatx4 acc[4][2];
    floatx4 zero = {0.f, 0.f, 0.f, 0.f};
#pragma unroll
    for (int i = 0; i < 4; ++i)
#pragma unroll
        for (int j = 0; j < 2; ++j) acc[i][j] = zero;

#pragma unroll
    for (int ks = 0; ks < 4; ++ks) {
        const int kc = ks * 32 + lq * 8;
        short8 bh[2], bl[2];
#pragma unroll
        for (int j = 0; j < 2; ++j) {
            long bo = (long)(wn + j * 16 + lm) * 128 + kc;
            bh[j] = *(const short8*)(Bh_g + bo);
            bl[j] = *(const short8*)(Bl_g + bo);
        }
        short8 ah[4], al[4];
#pragma unroll
        for (int i = 0; i < 4; ++i) {
            int gm = m0 + i * 16 + lm;
            float4 t0 = {0.f, 0.f, 0.f, 0.f}, t1 = {0.f, 0.f, 0.f, 0.f};
            if (gm < M) {
                const float* ap = A + (long)gm * 128 + kc;
                t0 = *(const float4*)ap;
                t1 = *(const float4*)(ap + 4);
            }
            short8 h, l;
            float f;
            f = t0.x; h[0] = f2bf(f); l[0] = f2bf(f - bf2f(h[0]));
            f = t0.y; h[1] = f2bf(f); l[1] = f2bf(f - bf2f(h[1]));
            f = t0.z; h[2] = f2bf(f); l[2] = f2bf(f - bf2f(h[2]));
            f = t0.w; h[3] = f2bf(f); l[3] = f2bf(f - bf2f(h[3]));
            f = t1.x; h[4] = f2bf(f); l[4] = f2bf(f - bf2f(h[4]));
            f = t1.y; h[5] = f2bf(f); l[5] = f2bf(f - bf2f(h[5]));
            f = t1.z; h[6] = f2bf(f); l[6] = f2bf(f - bf2f(h[6]));
            f = t1.w; h[7] = f2bf(f); l[7] = f2bf(f - bf2f(h[7]));
            ah[i] = h; al[i] = l;
        }
#pragma unroll
        for (int i = 0; i < 4; ++i)
#pragma unroll
            for (int j = 0; j < 2; ++j) {
                acc[i][j] = __builtin_amdgcn_mfma_f32_16x16x32_bf16(ah[i], bh[j], acc[i][j], 0, 0, 0);
                acc[i][j] = __builtin_amdgcn_mfma_f32_16x16x32_bf16(al[i], bh[j], acc[i][j], 0, 0, 0);
                acc[i][j] = __builtin_amdgcn_mfma_f32_16x16x32_bf16(ah[i], bl[j], acc[i][j], 0, 0, 0);
            }
    }

    __shared__ float sps[64][5], spd[64][5];
    float bv[2], wsv[2], wdv[2];
#pragma unroll
    for (int j = 0; j < 2; ++j) {
        int gn = wn + j * 16 + lm;
        bv[j] = bias[gn];
        wsv[j] = was[gn];
        wdv[j] = wad[gn];
    }
#pragma unroll
    for (int i = 0; i < 4; ++i) {
#pragma unroll
        for (int r = 0; r < 4; ++r) {
            int gm = m0 + i * 16 + lq * 4 + r;
            float vs = 0.f, vd = 0.f;
#pragma unroll
            for (int j = 0; j < 2; ++j) {
                int gn = wn + j * 16 + lm;
                float v = fmaxf(acc[i][j][r] + bv[j], 0.f);
                if (gm < M) C[(long)gm * 256 + gn] = v;
                vs = fmaf(v, wsv[j], vs);
                vd = fmaf(v, wdv[j], vd);
            }
#pragma unroll
            for (int o = 8; o; o >>= 1) {
                vs += __shfl_xor(vs, o);
                vd += __shfl_xor(vd, o);
            }
            if (lm == 0) {
                sps[i * 16 + lq * 4 + r][wave] = vs;
                spd[i * 16 + lq * 4 + r][wave] = vd;
            }
        }
    }
    __syncthreads();
    if (tid < 64) {
        int gm = m0 + tid;
        if (gm < M) {
            float s = sps[tid][0] + sps[tid][1] + sps[tid][2] + sps[tid][3];
            float d2 = spd[tid][0] + spd[tid][1] + spd[tid][2] + spd[tid][3];
            atomicAdd(das + gm, s);
            atomicAdd(dad + gm, d2);
        }
    }
}

// ---------------- GEMM via split-bf16 MFMA ----------------------------------
// r12: r9 core kept verbatim (measured best: cW1 75us, Occ 41%). New fused
// epilogues to shorten the serial dispatch chain:
//   FATT: att-scalar partial dots vs was/wad -> atomicAdd oas/oad (pre-zeroed)
//   HDOT: final head dot vs hw -> atomicAdd hout (pre-zeroed); no C write;
//         block n0==0/wave0 adds hb[0] once per row.
template<int ACT, int OSPLIT, int FATT, int HDOT>
__global__ __launch_bounds__(256, 6) void gemm2(
    const unsigned short* __restrict__ Ah_g, const unsigned short* __restrict__ Al_g,
    const unsigned short* __restrict__ Bh_g, const unsigned short* __restrict__ Bl_g,
    const float* __restrict__ bias,
    float* __restrict__ C, unsigned short* __restrict__ Ch_g, unsigned short* __restrict__ Cl_g,
    const float* __restrict__ was, const float* __restrict__ wad,
    float* __restrict__ oas, float* __restrict__ oad,
    const float* __restrict__ hw, const float* __restrict__ hb, float* __restrict__ hout,
    int M, int K, int N, int Kp, int Cs)
{
    __shared__ unsigned short Ah[2048];   // [64 rows][32 k]
    __shared__ unsigned short Al[2048];
    __shared__ unsigned short Bh[4096];   // [128 rows][32 k]
    __shared__ unsigned short Bl[4096];
    const int tid = threadIdx.x;
    const int wave = tid >> 6, lane = tid & 63;
    const int lm = lane & 15, lq = lane >> 4;
    const int wn = wave * 32;
    const int nx = gridDim.x;
    const int lin = blockIdx.y * nx + blockIdx.x;
    const int sup = lin / (8 * nx);
    const int wit = lin - sup * 8 * nx;
    const int rowb = sup * 8 + (wit & 7);
    const int nb = wit >> 3;
    const int m0 = rowb * 64, n0 = nb * 128;
    if (m0 >= M) return;

    floatx4 acc[4][2];
    floatx4 zero = {0.f, 0.f, 0.f, 0.f};
#pragma unroll
    for (int i = 0; i < 4; ++i)
#pragma unroll
        for (int j = 0; j < 2; ++j) acc[i][j] = zero;

    const int srow = lane >> 2;
    const int sslot = (lane & 3) ^ ((lane >> 3) & 3);
    const unsigned short* agh = Ah_g + (long)(m0 + wave * 16 + srow) * Kp + sslot * 8;
    const unsigned short* agl = Al_g + (long)(m0 + wave * 16 + srow) * Kp + sslot * 8;
    const unsigned short* bgh0 = Bh_g + (long)(n0 + wave * 32 + srow) * Kp + sslot * 8;
    const unsigned short* bgh1 = Bh_g + (long)(n0 + wave * 32 + 16 + srow) * Kp + sslot * 8;
    const unsigned short* bgl0 = Bl_g + (long)(n0 + wave * 32 + srow) * Kp + sslot * 8;
    const unsigned short* bgl1 = Bl_g + (long)(n0 + wave * 32 + 16 + srow) * Kp + sslot * 8;
    unsigned short* lAh = &Ah[wave * 512];
    unsigned short* lAl = &Al[wave * 512];
    unsigned short* lBh0 = &Bh[wave * 1024];
    unsigned short* lBh1 = &Bh[wave * 1024 + 512];
    unsigned short* lBl0 = &Bl[wave * 1024];
    unsigned short* lBl1 = &Bl[wave * 1024 + 512];
    const int xa = (lm >> 1) & 3;

    for (int k0 = 0; k0 < K; k0 += 32) {
        gll16(agh + k0, lAh);
        gll16(agl + k0, lAl);
        gll16(bgh0 + k0, lBh0);
        gll16(bgh1 + k0, lBh1);
        gll16(bgl0 + k0, lBl0);
        gll16(bgl1 + k0, lBl1);
        __syncthreads();
        short8 fah[4], fal[4], fbh[2], fbl[2];
#pragma unroll
        for (int i = 0; i < 4; ++i) {
            int off = (i * 16 + lm) * 32 + ((lq ^ xa) << 3);
            fah[i] = *(const short8*)&Ah[off];
            fal[i] = *(const short8*)&Al[off];
        }
#pragma unroll
        for (int j = 0; j < 2; ++j) {
            int off = (wn + j * 16 + lm) * 32 + ((lq ^ xa) << 3);
            fbh[j] = *(const short8*)&Bh[off];
            fbl[j] = *(const short8*)&Bl[off];
        }
#pragma unroll
        for (int i = 0; i < 4; ++i)
#pragma unroll
            for (int j = 0; j < 2; ++j) {
                acc[i][j] = __builtin_amdgcn_mfma_f32_16x16x32_bf16(fah[i], fbh[j], acc[i][j], 0, 0, 0);
                acc[i][j] = __builtin_amdgcn_mfma_f32_16x16x32_bf16(fal[i], fbh[j], acc[i][j], 0, 0, 0);
                acc[i][j] = __builtin_amdgcn_mfma_f32_16x16x32_bf16(fah[i], fbl[j], acc[i][j], 0, 0, 0);
            }
        __syncthreads();
    }
    // ---- epilogue: C/D layout col=lane&15, row=quad*4+reg (m89-verified) ----
    float bv[2], wsv[2], wdv[2], hwv[2];
#pragma unroll
    for (int j = 0; j < 2; ++j) {
        int gn = n0 + wn + j * 16 + lm;
        bv[j] = bias ? bias[gn] : 0.f;
        if (FATT) { wsv[j] = was[gn]; wdv[j] = wad[gn]; }
        if (HDOT) { hwv[j] = hw[gn]; }
    }
#pragma unroll
    for (int i = 0; i < 4; ++i) {
#pragma unroll
        for (int r = 0; r < 4; ++r) {
            int gm = m0 + i * 16 + lq * 4 + r;
            float vs = 0.f, vd = 0.f, hp = 0.f;
#pragma unroll
            for (int j = 0; j < 2; ++j) {
                int gn = n0 + wn + j * 16 + lm;
                float v = acc[i][j][r] + bv[j];
                if (ACT == 1) v = fmaxf(v, 0.f);
                if (ACT == 2) v = v > 0.f ? v : expm1f(v);
                if (!HDOT && gm < M) {
                    if (OSPLIT) {
                        long o = (long)gm * Cs + gn;
                        unsigned short h = f2bf(v);
                        Ch_g[o] = h;
                        Cl_g[o] = f2bf(v - bf2f(h));
                    } else {
                        C[(long)gm * (long)Cs + gn] = v;
                    }
                }
                if (FATT) { vs = fmaf(v, wsv[j], vs); vd = fmaf(v, wdv[j], vd); }
                if (HDOT) { hp = fmaf(v, hwv[j], hp); }
            }
            if (FATT) {
#pragma unroll
                for (int o = 8; o; o >>= 1) {
                    vs += __shfl_xor(vs, o);
                    vd += __shfl_xor(vd, o);
                }
                if (lm == 0 && gm < M) {
                    atomicAdd(oas + gm, vs);
                    atomicAdd(oad + gm, vd);
                }
            }
            if (HDOT) {
#pragma unroll
                for (int o = 8; o; o >>= 1) hp += __shfl_xor(hp, o);
                if (lm == 0 && gm < M) {
                    float add = hp;
                    if (n0 == 0 && wave == 0) add += hb[0];
                    atomicAdd(hout + gm, add);
                }
            }
        }
    }
}

// ---------------- combined CSR build (both graphs, by dst) ------------------
__global__ __launch_bounds__(256) void hist2_kernel(
    const int* __restrict__ ddst, int* __restrict__ dcnt, int ED, int ND,
    const int* __restrict__ cdst, int* __restrict__ ccnt, int EC, int NC)
{
    int t = blockIdx.x * 256 + threadIdx.x;
    int tot1 = ED + ND;
    if (t < tot1) {
        int d = t < ED ? ddst[t] : (t - ED);
        atomicAdd(&dcnt[d], 1);
    } else {
        int u = t - tot1;
        if (u < EC + NC) {
            int d = u < EC ? cdst[u] : (u - EC);
            atomicAdd(&ccnt[d], 1);
        }
    }
}

__device__ __forceinline__ void scan1_body(
    const int* cnt, int* off, int* bsum, int n, int b, int t)
{
    __shared__ int s[256];
    int i = b * 256 + t;
    int v = (i < n) ? cnt[i] : 0;
    s[t] = v;
    __syncthreads();
    for (int d = 1; d < 256; d <<= 1) {
        int u = (t >= d) ? s[t - d] : 0;
        __syncthreads();
        s[t] += u;
        __syncthreads();
    }
    if (i < n) off[i] = s[t] - v;
    if (t == 255) bsum[b] = s[255];
}

__global__ __launch_bounds__(256) void scan1both_kernel(
    const int* __restrict__ dcnt, int* __restrict__ doff, int* __restrict__ bsum_d, int ND, int nbd,
    const int* __restrict__ ccnt, int* __restrict__ coff, int* __restrict__ bsum_c, int NC)
{
    int b = blockIdx.x, t = threadIdx.x;
    if (b < nbd) scan1_body(dcnt, doff, bsum_d, ND, b, t);
    else         scan1_body(ccnt, coff, bsum_c, NC, b - nbd, t);
}

__device__ __forceinline__ void scan2_body(
    const int* bsum, int* bpre, int nb, int* off, int n, int t)
{
    __shared__ int s[256];
    int v = (t < nb) ? bsum[t] : 0;
    s[t] = v;
    __syncthreads();
    for (int d = 1; d < 256; d <<= 1) {
        int u = (t >= d) ? s[t - d] : 0;
        __syncthreads();
        s[t] += u;
        __syncthreads();
    }
    if (t < nb) bpre[t] = s[t] - v;
    if (t == 255) off[n] = s[255];
}

__global__ __launch_bounds__(256) void scan2both_kernel(
    const int* __restrict__ bsum_d, int* __restrict__ bpre_d, int nbd, int* __restrict__ doff, int ND,
    const int* __restrict__ bsum_c, int* __restrict__ bpre_c, int nbc, int* __restrict__ coff, int NC)
{
    int t = threadIdx.x;
    if (blockIdx.x == 0) scan2_body(bsum_d, bpre_d, nbd, doff, ND, t);
    else                 scan2_body(bsum_c, bpre_c, nbc, coff, NC, t);
}

__global__ __launch_bounds__(256) void scan3both_kernel(
    int* __restrict__ doff, int* __restrict__ dcur, const int* __restrict__ bpre_d, int ND, int nbd,
    int* __restrict__ coff, int* __restrict__ ccur, const int* __restrict__ bpre_c, int NC)
{
    int b = blockIdx.x, t = threadIdx.x;
    if (b < nbd) {
        int i = b * 256 + t;
        if (i < ND) {
            int v = doff[i] + bpre_d[b];
            doff[i] = v;
            dcur[i] = v;
        }
    } else {
        int i = (b - nbd) * 256 + t;
        if (i < NC) {
            int v = coff[i] + bpre_c[b - nbd];
            coff[i] = v;
            ccur[i] = v;
        }
    }
}

__global__ __launch_bounds__(256) void scatter2_kernel(
    const int* __restrict__ dsrc, const int* __restrict__ ddst,
    int* __restrict__ dcur, int* __restrict__ debuf, int ED, int ND,
    const int* __restrict__ csrc, const int* __restrict__ cdst,
    int* __restrict__ ccur, int* __restrict__ cebuf, int EC, int NC)
{
    int t = blockIdx.x * 256 + threadIdx.x;
    int tot1 = ED + ND;
    if (t < tot1) {
        int s = t < ED ? dsrc[t] : (t - ED);
        int d = t < ED ? ddst[t] : (t - ED);
        int pos = atomicAdd(&dcur[d], 1);
        debuf[pos] = s;
    } else {
        int u = t - tot1;
        if (u < EC + NC) {
            int s = u < EC ? csrc[u] : (u - EC);
            int d = u < EC ? cdst[u] : (u - EC);
            int pos = atomicAdd(&ccur[d], 1);
            cebuf[pos] = s;
        }
    }
}

// ------------- fused softmax + aggregate, one WAVE per output row -----------
template<int EPI>
__global__ __launch_bounds__(256) void gat_agg3(
    const int* __restrict__ off, const int* __restrict__ ebuf,
    const float* __restrict__ as_, const float* __restrict__ ad_,
    const float* __restrict__ x, const float* __restrict__ bias,
    const int* __restrict__ dmap,
    float* __restrict__ outF, unsigned short* __restrict__ outH,
    unsigned short* __restrict__ outL, int nrows)
{
    int row = blockIdx.x * 4 + (threadIdx.x >> 6);
    int lane = threadIdx.x & 63;
    if (row >= nrows) return;
    int d = dmap ? dmap[row] : row;
    int lo = off[d], hi = off[d + 1];
    float adv = ad_[d];

    float m = -INFINITY;
    for (int p = lo + lane; p < hi; p += 64)
        m = fmaxf(m, lrelu(as_[ebuf[p]] + adv));
#pragma unroll
    for (int o = 32; o; o >>= 1) m = fmaxf(m, __shfl_xor(m, o));

    const float* xb = x + lane * 4;
    float4 acc = {0.f, 0.f, 0.f, 0.f};
    float psum = 0.f;
    for (int base = lo; base < hi; base += 64) {
        int cnt = min(64, hi - base);
        int s = 0;
        float ex = 0.f;
        if (lane < cnt) {
            s = ebuf[base + lane];
            ex = expf(lrelu(as_[s] + adv) - m);
        }
        psum += ex;
        for (int i = 0; i < cnt; ++i) {
            int si = __shfl(s, i);
            float ei = __shfl(ex, i);
            float4 v = *(const float4*)(xb + (long)si * 256);
            acc.x = fmaf(ei, v.x, acc.x);
            acc.y = fmaf(ei, v.y, acc.y);
            acc.z = fmaf(ei, v.z, acc.z);
            acc.w = fmaf(ei, v.w, acc.w);
        }
    }
#pragma unroll
    for (int o = 32; o; o >>= 1) psum += __shfl_xor(psum, o);
    float inv = 1.f / psum;

    long ob = (long)row * 256 + lane * 4;
    if (EPI == 1) {
        float r0 = fmaxf(acc.x * inv + bias[lane * 4 + 0], 0.f);
        float r1 = fmaxf(acc.y * inv + bias[lane * 4 + 1], 0.f);
        float r2 = fmaxf(acc.z * inv + bias[lane * 4 + 2], 0.f);
        float r3 = fmaxf(acc.w * inv + bias[lane * 4 + 3], 0.f);
        float4 r = {r0, r1, r2, r3};
        *(float4*)(outF + ob) = r;
    } else {
        float vv[4] = {acc.x * inv, acc.y * inv, acc.z * inv, acc.w * inv};
#pragma unroll
        for (int j = 0; j < 4; ++j) {
            unsigned short h = f2bf(vv[j]);
            outH[ob + j] = h;
            outL[ob + j] = f2bf(vv[j] - bf2f(h));
        }
    }
}

// comb right half, 4 rows per block: comb[i][256+c] = split(cfin[cidx[i]][c])
__global__ __launch_bounds__(256) void gather_cell_split4(
    const float* __restrict__ cfin, const int* __restrict__ cidx,
    unsigned short* __restrict__ combH, unsigned short* __restrict__ combL)
{
    int row = blockIdx.x * 4 + (threadIdx.x >> 6);
    int lane = threadIdx.x & 63;
    float4 v = *(const float4*)(cfin + (long)cidx[row] * 256 + lane * 4);
    long b = (long)row * 512 + 256 + lane * 4;
    float vv[4] = {v.x, v.y, v.z, v.w};
#pragma unroll
    for (int j = 0; j < 4; ++j) {
        unsigned short h = f2bf(vv[j]);
        combH[b + j] = h;
        combL[b + j] = f2bf(vv[j] - bf2f(h));
    }
}

// ------------------------------ orchestration -------------------------------
static inline dim3 mfma_grid64(int M, int N) {
    int ny = (M + 63) / 64;
    ny = (ny + 7) & ~7;
    return dim3(N / 128, ny);
}

extern "C" void kernel_launch(void* const* d_in, const int* in_sizes, int n_in,
                              void* d_out, int out_size, void* d_ws, size_t ws_size,
                              hipStream_t stream)
{
    const float* drug_x = (const float*)d_in[0];
    const float* cell_x = (const float*)d_in[1];
    const int* d_ei = (const int*)d_in[2];
    const int* c_ei = (const int*)d_in[3];
    const int* d_idx = (const int*)d_in[4];
    const int* c_idx = (const int*)d_in[5];
    const float* dW1 = (const float*)d_in[6];
    const float* db1 = (const float*)d_in[7];
    const float* cW1 = (const float*)d_in[8];
    const float* cb1 = (const float*)d_in[9];
    const float* cW2 = (const float*)d_in[10];
    const float* cb2 = (const float*)d_in[11];
    const float* gdW = (const float*)d_in[12];
    const float* gdas = (const float*)d_in[13];
    const float* gdad = (const float*)d_in[14];
    const float* gdb = (const float*)d_in[15];
    const float* g1W = (const float*)d_in[16];
    const float* g1as = (const float*)d_in[17];
    const float* g1ad = (const float*)d_in[18];
    const float* g1b = (const float*)d_in[19];
    const float* g2W = (const float*)d_in[20];
    const float* g2as = (const float*)d_in[21];
    const float* g2ad = (const float*)d_in[22];
    const float* g2b = (const float*)d_in[23];
    const float* rW1 = (const float*)d_in[24];
    const float* rb1 = (const float*)d_in[25];
    const float* rW2 = (const float*)d_in[26];
    const float* rb2 = (const float*)d_in[27];
    const float* rW3 = (const float*)d_in[28];
    const float* rb3 = (const float*)d_in[29];

    const int ND = in_sizes[0] / 128;     // 50000
    const int NC = in_sizes[1] / 735;     // 10000
    const int ED = in_sizes[2] / 2;       // 800000
    const int EC = in_sizes[3] / 2;       // 160000
    const int NB = in_sizes[4];           // 16384

    const int* d_src = d_ei;
    const int* d_dst = d_ei + ED;
    const int* c_src = c_ei;
    const int* c_dst = c_ei + EC;

    const size_t MB = 1ull << 20;
    const size_t KB = 1024;
    char* ws = (char*)d_ws;

    // ---- weight split region [0, 9MB) ----
    size_t wo = 0;
    auto walloc = [&](size_t elems) -> unsigned short* {
        unsigned short* p = (unsigned short*)(ws + wo);
        wo += ((elems * 2 + 255) & ~(size_t)255);
        return p;
    };
    unsigned short* dW1h = walloc(256 * 128);  unsigned short* dW1l = walloc(256 * 128);
    unsigned short* cW1h = walloc(1024 * 736); unsigned short* cW1l = walloc(1024 * 736);
    unsigned short* cW2h = walloc(256 * 1024); unsigned short* cW2l = walloc(256 * 1024);
    unsigned short* gdWh = walloc(256 * 256);  unsigned short* gdWl = walloc(256 * 256);
    unsigned short* g1Wh = walloc(1024 * 256); unsigned short* g1Wl = walloc(1024 * 256);
    unsigned short* g2Wh = walloc(256 * 1024); unsigned short* g2Wl = walloc(256 * 1024);
    unsigned short* rW1h = walloc(512 * 512);  unsigned short* rW1l = walloc(512 * 512);
    unsigned short* rW2h = walloc(512 * 512);  unsigned short* rW2l = walloc(512 * 512);

    // ---- small scratch (not zeroed) [9, 11MB) ----
    float* wa_ds  = (float*)(ws + 9 * MB);
    float* wa_dd  = (float*)(ws + 9 * MB + 4 * KB);
    float* wa_c1s = (float*)(ws + 9 * MB + 8 * KB);
    float* wa_c1d = (float*)(ws + 9 * MB + 12 * KB);
    int*   bsum_d = (int*)(ws + 9 * MB + 400 * KB);
    int*   bpre_d = (int*)(ws + 9 * MB + 404 * KB);
    int*   bsum_c = (int*)(ws + 9 * MB + 408 * KB);
    int*   bpre_c = (int*)(ws + 9 * MB + 412 * KB);
    int*   doff   = (int*)(ws + 9 * MB + 448 * KB);   // ND+1 ints
    int*   dcur   = (int*)(ws + 9 * MB + 704 * KB);
    int*   cebuf  = (int*)(ws + 10 * MB);              // EC+NC ints (~680KB)
    int*   coff   = (int*)(ws + 10 * MB + 768 * KB);   // NC+1 ints
    int*   ccur   = (int*)(ws + 10 * MB + 832 * KB);
    // ---- zero block [11MB, 11MB+960KB): one memset covers all ----
    float* das    = (float*)(ws + 11 * MB);
    float* dad    = (float*)(ws + 11 * MB + 256 * KB);
    int*   dcnt   = (int*)(ws + 11 * MB + 512 * KB);
    int*   ccnt   = (int*)(ws + 11 * MB + 768 * KB);
    float* cas    = (float*)(ws + 11 * MB + 832 * KB);
    float* cad    = (float*)(ws + 11 * MB + 896 * KB);
    int*   debuf  = (int*)(ws + 12 * MB);              // ED+ND ints (~3.4MB) -> <16MB

    // ---- big buffers (liveness-checked) ----
    float* dbuf  = (float*)(ws + 16 * MB);                    // d0 [ND,256] [16,65)
    unsigned short* aggdh = (unsigned short*)(ws + 66 * MB);  // [NB,256]
    unsigned short* aggdl = (unsigned short*)(ws + 75 * MB);
    unsigned short* combh = (unsigned short*)(ws + 84 * MB);  // [NB,512]
    unsigned short* combl = (unsigned short*)(ws + 101 * MB);
    unsigned short* c0h = (unsigned short*)(ws + 16 * MB);    // (dbuf dead)
    unsigned short* c0l = (unsigned short*)(ws + 36 * MB);
    float* c1b   = (float*)(ws + 118 * MB);                   // [NC,256]
    unsigned short* aggch = (unsigned short*)(ws + 129 * MB);
    unsigned short* aggcl = (unsigned short*)(ws + 135 * MB);
    unsigned short* c2h = (unsigned short*)(ws + 16 * MB);    // (c0 dead)
    unsigned short* c2l = (unsigned short*)(ws + 36 * MB);
    float* xc2   = (float*)(ws + 118 * MB);                   // (c1 dead)
    float* cfin  = (float*)(ws + 141 * MB);
    unsigned short* h1h = (unsigned short*)(ws + 16 * MB);    // (c2 dead)
    unsigned short* h1l = (unsigned short*)(ws + 33 * MB);
    unsigned short* cxh = (unsigned short*)(ws + 152 * MB);   // cell_x split
    unsigned short* cxl = (unsigned short*)(ws + 167 * MB);

    // ====================== memsets (2 total) ==============================
    hipMemsetAsync(ws + 11 * MB, 0, 960 * KB, stream);
    hipMemsetAsync(d_out, 0, (size_t)NB * 4, stream);

    // ================= fused prepass: 8 splits + 4 matvecs ==================
    SJobs js;
    js.j[0] = {dW1, dW1h, dW1l, 128, 256, 128, 0};
    js.j[1] = {cW1, cW1h, cW1l, 735, 1024, 736, 32};
    js.j[2] = {cW2, cW2h, cW2l, 1024, 256, 1024, 768};
    js.j[3] = {gdW, gdWh, gdWl, 256, 256, 256, 1024};
    js.j[4] = {g1W, g1Wh, g1Wl, 256, 1024, 256, 1088};
    js.j[5] = {g2W, g2Wh, g2Wl, 1024, 256, 1024, 1344};
    js.j[6] = {rW1, rW1h, rW1l, 512, 512, 512, 1600};
    js.j[7] = {rW2, rW2h, rW2l, 512, 512, 512, 1856};
    split_transpose_multi<<<2112, 256, 0, stream>>>(js);
    split_cell_rows<<<NC, 256, 0, stream>>>(cell_x, cxh, cxl, NC);
    matvec4<<<1024, 256, 0, stream>>>(gdW, gdas, gdad, wa_ds, wa_dd,
                                      g1W, g1as, g1ad, wa_c1s, wa_c1d);

    // ================= combined CSR build (both graphs) =====================
    {
        int nbd = (ND + 255) / 256, nbc = (NC + 255) / 256;
        int tot = (ED + ND) + (EC + NC);
        hist2_kernel<<<(tot + 255) / 256, 256, 0, stream>>>(
            d_dst, dcnt, ED, ND, c_dst, ccnt, EC, NC);
        scan1both_kernel<<<nbd + nbc, 256, 0, stream>>>(
            dcnt, doff, bsum_d, ND, nbd, ccnt, coff, bsum_c, NC);
        scan2both_kernel<<<2, 256, 0, stream>>>(
            bsum_d, bpre_d, nbd, doff, ND, bsum_c, bpre_c, nbc, coff, NC);
        scan3both_kernel<<<nbd + nbc, 256, 0, stream>>>(
            doff, dcur, bpre_d, ND, nbd, coff, ccur, bpre_c, NC);
        scatter2_kernel<<<(tot + 255) / 256, 256, 0, stream>>>(
            d_src, d_dst, dcur, debuf, ED, ND,
            c_src, c_dst, ccur, cebuf, EC, NC);
    }

    // ======================= drug path (batch-sparse) =======================
    {
        int nblk = 2 * ((ND + 63) / 64);
        gemm_d0_fused<<<nblk, 256, 0, stream>>>(
            drug_x, dW1h, dW1l, db1, wa_ds, wa_dd, dbuf, das, dad, ND, nblk);
    }
    gat_agg3<0><<<(NB + 3) / 4, 256, 0, stream>>>(doff, debuf, das, dad, dbuf, nullptr,
                                                  d_idx, nullptr, aggdh, aggdl, NB);
    gemm2<1, 1, 0, 0><<<mfma_grid64(NB, 256), 256, 0, stream>>>(
        aggdh, aggdl, gdWh, gdWl, gdb, nullptr, combh, combl,
        nullptr, nullptr, nullptr, nullptr, nullptr, nullptr, nullptr,
        NB, 256, 256, 256, 512);

    // ======================= cell path =======================
    gemm2<1, 1, 0, 0><<<mfma_grid64(NC, 1024), 256, 0, stream>>>(
        cxh, cxl, cW1h, cW1l, cb1, nullptr, c0h, c0l,
        nullptr, nullptr, nullptr, nullptr, nullptr, nullptr, nullptr,
        NC, 736, 1024, 736, 1024);
    // cW2 with fused att-scalars (cas/cad pre-zeroed)
    gemm2<1, 0, 1, 0><<<mfma_grid64(NC, 256), 256, 0, stream>>>(
        c0h, c0l, cW2h, cW2l, cb2, c1b, nullptr, nullptr,
        wa_c1s, wa_c1d, cas, cad, nullptr, nullptr, nullptr,
        NC, 1024, 256, 1024, 256);
    gat_agg3<0><<<(NC + 3) / 4, 256, 0, stream>>>(coff, cebuf, cas, cad, c1b, nullptr,
                                                  nullptr, nullptr, aggch, aggcl, NC);
    gemm2<1, 1, 0, 0><<<mfma_grid64(NC, 1024), 256, 0, stream>>>(
        aggch, aggcl, g1Wh, g1Wl, g1b, nullptr, c2h, c2l,
        nullptr, nullptr, nullptr, nullptr, nullptr, nullptr, nullptr,
        NC, 256, 1024, 256, 1024);
    // re-zero cas/cad for the second att pass, then g2 with fused att
    hipMemsetAsync(ws + 11 * MB + 832 * KB, 0, 128 * KB, stream);
    gemm2<0, 0, 1, 0><<<mfma_grid64(NC, 256), 256, 0, stream>>>(
        c2h, c2l, g2Wh, g2Wl, nullptr, xc2, nullptr, nullptr,
        g2as, g2ad, cas, cad, nullptr, nullptr, nullptr,
        NC, 1024, 256, 1024, 256);
    gat_agg3<1><<<(NC + 3) / 4, 256, 0, stream>>>(coff, cebuf, cas, cad, xc2, g2b,
                                                  nullptr, cfin, nullptr, nullptr, NC);

    // ======================= head =======================
    gather_cell_split4<<<NB / 4, 256, 0, stream>>>(cfin, c_idx, combh, combl);
    gemm2<2, 1, 0, 0><<<mfma_grid64(NB, 512), 256, 0, stream>>>(
        combh, combl, rW1h, rW1l, rb1, nullptr, h1h, h1l,
        nullptr, nullptr, nullptr, nullptr, nullptr, nullptr, nullptr,
        NB, 512, 512, 512, 512);
    // rW2 with fused elu + final dot into d_out (pre-zeroed)
    gemm2<2, 0, 0, 1><<<mfma_grid64(NB, 512), 256, 0, stream>>>(
        h1h, h1l, rW2h, rW2l, rb2, nullptr, nullptr, nullptr,
        nullptr, nullptr, nullptr, nullptr, rW3, rb3, (float*)d_out,
        NB, 512, 512, 512, 512);
}

// Round 13
// 665.701 us; speedup vs baseline: 1.1482x; 1.0347x over previous
//
#include <hip/hip_runtime.h>
#include <math.h>

#define NEG_SLOPE 0.2f

typedef __attribute__((ext_vector_type(8))) short short8;
typedef __attribute__((ext_vector_type(4))) float floatx4;

// ---------------- fp32 <-> bf16 split helpers (RNE) ----------------
__device__ __forceinline__ unsigned short f2bf(float f) {
    unsigned u = __float_as_uint(f);
    u += 0x7fffu + ((u >> 16) & 1u);
    return (unsigned short)(u >> 16);
}
__device__ __forceinline__ float bf2f(unsigned short h) {
    return __uint_as_float((unsigned)h << 16);
}
__device__ __forceinline__ float lrelu(float v) {
    return v > 0.f ? v : NEG_SLOPE * v;
}

// ---- async global->LDS, 16B per lane (gfx950). dest = uniform base + lane*16
typedef __attribute__((address_space(3))) unsigned int lds_u32;
typedef const __attribute__((address_space(1))) unsigned int glb_u32c;
__device__ __forceinline__ void gll16(const unsigned short* g, unsigned short* l) {
    __builtin_amdgcn_global_load_lds((glb_u32c*)g, (lds_u32*)l, 16, 0, 0);
}

// ---------------- merged prepass: 8 splits + cell_x split + 4 matvecs -------
// r13: one launch replaces split_transpose_multi / split_cell_rows / matvec4.
struct SJob { const float* W; unsigned short* Th; unsigned short* Tl; int K, N, Kp, base; };
struct SJobs { SJob j[8]; };

__global__ __launch_bounds__(256) void prepass_all(
    SJobs js, int nst,                                    // split-transpose blocks
    const float* __restrict__ cellx, unsigned short* __restrict__ cxh,
    unsigned short* __restrict__ cxl, int NC,
    const float* __restrict__ gdW, const float* __restrict__ gdas, const float* __restrict__ gdad,
    float* __restrict__ wds, float* __restrict__ wdd,
    const float* __restrict__ g1W, const float* __restrict__ g1as, const float* __restrict__ g1ad,
    float* __restrict__ w1s, float* __restrict__ w1d)
{
    __shared__ float tbuf[32][33];
    int blk = blockIdx.x;
    if (blk < nst) {
        // ---- split-transpose job ----
        int t = blk;
        int ji = 0;
#pragma unroll
        for (int q = 1; q < 8; ++q) if (t >= js.j[q].base) ji = q;
        const SJob jb = js.j[ji];
        int local = t - jb.base;
        int ntiles = jb.N / 32;
        int tn = local % ntiles, tk = local / ntiles;
        int k0 = tk * 32, n0 = tn * 32;
        int c = threadIdx.x & 31, r = threadIdx.x >> 5;
        for (int rr = r; rr < 32; rr += 8) {
            int k = k0 + rr, n = n0 + c;
            tbuf[rr][c] = (k < jb.K && n < jb.N) ? jb.W[(long)k * jb.N + n] : 0.f;
        }
        __syncthreads();
        for (int rr = r; rr < 32; rr += 8) {
            int n = n0 + rr, k = k0 + c;
            if (n < jb.N && k < jb.Kp) {
                float v = tbuf[c][rr];
                unsigned short h = f2bf(v);
                jb.Th[(long)n * jb.Kp + k] = h;
                jb.Tl[(long)n * jb.Kp + k] = f2bf(v - bf2f(h));
            }
        }
    } else if (blk < nst + NC) {
        // ---- cell_x row split: [735] fp32 -> [736] bf16 hi/lo ----
        long i = blk - nst;
        int t = threadIdx.x;
        const float* r = cellx + i * 735;
        for (int c = t; c < 736; c += 256) {
            float v = (c < 735) ? r[c] : 0.f;
            unsigned short h = f2bf(v);
            cxh[i * 736 + c] = h;
            cxl[i * 736 + c] = f2bf(v - bf2f(h));
        }
    } else {
        // ---- 4 fused matvecs ----
        int b = blk - nst - NC;
        int sel = b >> 8, k = b & 255, t = threadIdx.x;
        const float *W, *a; float* o; int N;
        if (sel == 0)      { W = gdW; a = gdas; o = wds; N = 256; }
        else if (sel == 1) { W = gdW; a = gdad; o = wdd; N = 256; }
        else if (sel == 2) { W = g1W; a = g1as; o = w1s; N = 1024; }
        else               { W = g1W; a = g1ad; o = w1d; N = 1024; }
        float s = 0.f;
        for (int n = t; n < N; n += 256) s += W[(long)k * N + n] * a[n];
#pragma unroll
        for (int off = 32; off; off >>= 1) s += __shfl_down(s, off);
        float* ls = &tbuf[0][0];
        if ((t & 63) == 0) ls[t >> 6] = s;
        __syncthreads();
        if (t == 0) o[k] = ls[0] + ls[1] + ls[2] + ls[3];
    }
}

// ======== merged d0 GEMM + CSR histogram (independent work, one launch) =====
// d0: M x 128 @ 128 x 256, no LDS in main loop, no barriers; fused att
// scalars. hist blocks (blk >= nblk) count dst degrees for both graphs.
__global__ __launch_bounds__(256, 3) void d0_hist(
    const float* __restrict__ A,
    const unsigned short* __restrict__ Bh_g,
    const unsigned short* __restrict__ Bl_g,
    const float* __restrict__ bias,
    const float* __restrict__ was, const float* __restrict__ wad,
    float* __restrict__ C,
    float* __restrict__ das, float* __restrict__ dad,
    int M, int nblk,
    const int* __restrict__ ddst, int* __restrict__ dcnt, int ED, int ND,
    const int* __restrict__ cdst, int* __restrict__ ccnt, int EC, int NC)
{
    if (blockIdx.x >= nblk) {
        // ---- histogram half ----
        int t = (blockIdx.x - nblk) * 256 + threadIdx.x;
        int tot1 = ED + ND;
        if (t < tot1) {
            int d = t < ED ? ddst[t] : (t - ED);
            atomicAdd(&dcnt[d], 1);
        } else {
            int u = t - tot1;
            if (u < EC + NC) {
                int d = u < EC ? cdst[u] : (u - EC);
                atomicAdd(&ccnt[d], 1);
            }
        }
        return;
    }
    int bid = blockIdx.x;
    int q = nblk >> 3, rr = nblk & 7;
    int xcd = bid & 7, idx = bid >> 3;
    int wg = (xcd < rr ? xcd * (q + 1) : rr * (q + 1) + (xcd - rr) * q) + idx;
    int rb = wg >> 1, colh = wg & 1;
    int m0 = rb * 64, n0 = colh * 128;
    if (m0 >= M) return;
    const int tid = threadIdx.x;
    const int wave = tid >> 6, lane = tid & 63;
    const int lm = lane & 15, lq = lane >> 4;
    const int wn = n0 + wave * 32;

    floatx4 acc[4][2];
    floatx4 zero = {0.f, 0.f, 0.f, 0.f};
#pragma unroll
    for (int i = 0; i < 4; ++i)
#pragma unroll
        for (int j = 0; j < 2; ++j) acc[i][j] = zero;

#pragma unroll
    for (int ks = 0; ks < 4; ++ks) {
        const int kc = ks * 32 + lq * 8;
        short8 bh[2], bl[2];
#pragma unroll
        for (int j = 0; j < 2; ++j) {
            long bo = (long)(wn + j * 16 + lm) * 128 + kc;
            bh[j] = *(const short8*)(Bh_g + bo);
            bl[j] = *(const short8*)(Bl_g + bo);
        }
        short8 ah[4], al[4];
#pragma unroll
        for (int i = 0; i < 4; ++i) {
            int gm = m0 + i * 16 + lm;
            float4 t0 = {0.f, 0.f, 0.f, 0.f}, t1 = {0.f, 0.f, 0.f, 0.f};
            if (gm < M) {
                const float* ap = A + (long)gm * 128 + kc;
                t0 = *(const float4*)ap;
                t1 = *(const float4*)(ap + 4);
            }
            short8 h, l;
            float f;
            f = t0.x; h[0] = f2bf(f); l[0] = f2bf(f - bf2f(h[0]));
            f = t0.y; h[1] = f2bf(f); l[1] = f2bf(f - bf2f(h[1]));
            f = t0.z; h[2] = f2bf(f); l[2] = f2bf(f - bf2f(h[2]));
            f = t0.w; h[3] = f2bf(f); l[3] = f2bf(f - bf2f(h[3]));
            f = t1.x; h[4] = f2bf(f); l[4] = f2bf(f - bf2f(h[4]));
            f = t1.y; h[5] = f2bf(f); l[5] = f2bf(f - bf2f(h[5]));
            f = t1.z; h[6] = f2bf(f); l[6] = f2bf(f - bf2f(h[6]));
            f = t1.w; h[7] = f2bf(f); l[7] = f2bf(f - bf2f(h[7]));
            ah[i] = h; al[i] = l;
        }
#pragma unroll
        for (int i = 0; i < 4; ++i)
#pragma unroll
            for (int j = 0; j < 2; ++j) {
                acc[i][j] = __builtin_amdgcn_mfma_f32_16x16x32_bf16(ah[i], bh[j], acc[i][j], 0, 0, 0);
                acc[i][j] = __builtin_amdgcn_mfma_f32_16x16x32_bf16(al[i], bh[j], acc[i][j], 0, 0, 0);
                acc[i][j] = __builtin_amdgcn_mfma_f32_16x16x32_bf16(ah[i], bl[j], acc[i][j], 0, 0, 0);
            }
    }

    __shared__ float sps[64][5], spd[64][5];
    float bv[2], wsv[2], wdv[2];
#pragma unroll
    for (int j = 0; j < 2; ++j) {
        int gn = wn + j * 16 + lm;
        bv[j] = bias[gn];
        wsv[j] = was[gn];
        wdv[j] = wad[gn];
    }
#pragma unroll
    for (int i = 0; i < 4; ++i) {
#pragma unroll
        for (int r = 0; r < 4; ++r) {
            int gm = m0 + i * 16 + lq * 4 + r;
            float vs = 0.f, vd = 0.f;
#pragma unroll
            for (int j = 0; j < 2; ++j) {
                int gn = wn + j * 16 + lm;
                float v = fmaxf(acc[i][j][r] + bv[j], 0.f);
                if (gm < M) C[(long)gm * 256 + gn] = v;
                vs = fmaf(v, wsv[j], vs);
                vd = fmaf(v, wdv[j], vd);
            }
#pragma unroll
            for (int o = 8; o; o >>= 1) {
                vs += __shfl_xor(vs, o);
                vd += __shfl_xor(vd, o);
            }
            if (lm == 0) {
                sps[i * 16 + lq * 4 + r][wave] = vs;
                spd[i * 16 + lq * 4 + r][wave] = vd;
            }
        }
    }
    __syncthreads();
    if (tid < 64) {
        int gm = m0 + tid;
        if (gm < M) {
            float s = sps[tid][0] + sps[tid][1] + sps[tid][2] + sps[tid][3];
            float d2 = spd[tid][0] + spd[tid][1] + spd[tid][2] + spd[tid][3];
            atomicAdd(das + gm, s);
            atomicAdd(dad + gm, d2);
        }
    }
}

// ---------------- GEMM via split-bf16 MFMA ----------------------------------
// r9 core (measured best). Fused epilogues: FATT att-scalar dots; HDOT final
// head dot into hout (pre-zeroed), no C write.
template<int ACT, int OSPLIT, int FATT, int HDOT>
__global__ __launch_bounds__(256, 6) void gemm2(
    const unsigned short* __restrict__ Ah_g, const unsigned short* __restrict__ Al_g,
    const unsigned short* __restrict__ Bh_g, const unsigned short* __restrict__ Bl_g,
    const float* __restrict__ bias,
    float* __restrict__ C, unsigned short* __restrict__ Ch_g, unsigned short* __restrict__ Cl_g,
    const float* __restrict__ was, const float* __restrict__ wad,
    float* __restrict__ oas, float* __restrict__ oad,
    const float* __restrict__ hw, const float* __restrict__ hb, float* __restrict__ hout,
    int M, int K, int N, int Kp, int Cs)
{
    __shared__ unsigned short Ah[2048];   // [64 rows][32 k]
    __shared__ unsigned short Al[2048];
    __shared__ unsigned short Bh[4096];   // [128 rows][32 k]
    __shared__ unsigned short Bl[4096];
    const int tid = threadIdx.x;
    const int wave = tid >> 6, lane = tid & 63;
    const int lm = lane & 15, lq = lane >> 4;
    const int wn = wave * 32;
    const int nx = gridDim.x;
    const int lin = blockIdx.y * nx + blockIdx.x;
    const int sup = lin / (8 * nx);
    const int wit = lin - sup * 8 * nx;
    const int rowb = sup * 8 + (wit & 7);
    const int nb = wit >> 3;
    const int m0 = rowb * 64, n0 = nb * 128;
    if (m0 >= M) return;

    floatx4 acc[4][2];
    floatx4 zero = {0.f, 0.f, 0.f, 0.f};
#pragma unroll
    for (int i = 0; i < 4; ++i)
#pragma unroll
        for (int j = 0; j < 2; ++j) acc[i][j] = zero;

    const int srow = lane >> 2;
    const int sslot = (lane & 3) ^ ((lane >> 3) & 3);
    const unsigned short* agh = Ah_g + (long)(m0 + wave * 16 + srow) * Kp + sslot * 8;
    const unsigned short* agl = Al_g + (long)(m0 + wave * 16 + srow) * Kp + sslot * 8;
    const unsigned short* bgh0 = Bh_g + (long)(n0 + wave * 32 + srow) * Kp + sslot * 8;
    const unsigned short* bgh1 = Bh_g + (long)(n0 + wave * 32 + 16 + srow) * Kp + sslot * 8;
    const unsigned short* bgl0 = Bl_g + (long)(n0 + wave * 32 + srow) * Kp + sslot * 8;
    const unsigned short* bgl1 = Bl_g + (long)(n0 + wave * 32 + 16 + srow) * Kp + sslot * 8;
    unsigned short* lAh = &Ah[wave * 512];
    unsigned short* lAl = &Al[wave * 512];
    unsigned short* lBh0 = &Bh[wave * 1024];
    unsigned short* lBh1 = &Bh[wave * 1024 + 512];
    unsigned short* lBl0 = &Bl[wave * 1024];
    unsigned short* lBl1 = &Bl[wave * 1024 + 512];
    const int xa = (lm >> 1) & 3;

    for (int k0 = 0; k0 < K; k0 += 32) {
        gll16(agh + k0, lAh);
        gll16(agl + k0, lAl);
        gll16(bgh0 + k0, lBh0);
        gll16(bgh1 + k0, lBh1);
        gll16(bgl0 + k0, lBl0);
        gll16(bgl1 + k0, lBl1);
        __syncthreads();
        short8 fah[4], fal[4], fbh[2], fbl[2];
#pragma unroll
        for (int i = 0; i < 4; ++i) {
            int off = (i * 16 + lm) * 32 + ((lq ^ xa) << 3);
            fah[i] = *(const short8*)&Ah[off];
            fal[i] = *(const short8*)&Al[off];
        }
#pragma unroll
        for (int j = 0; j < 2; ++j) {
            int off = (wn + j * 16 + lm) * 32 + ((lq ^ xa) << 3);
            fbh[j] = *(const short8*)&Bh[off];
            fbl[j] = *(const short8*)&Bl[off];
        }
#pragma unroll
        for (int i = 0; i < 4; ++i)
#pragma unroll
            for (int j = 0; j < 2; ++j) {
                acc[i][j] = __builtin_amdgcn_mfma_f32_16x16x32_bf16(fah[i], fbh[j], acc[i][j], 0, 0, 0);
                acc[i][j] = __builtin_amdgcn_mfma_f32_16x16x32_bf16(fal[i], fbh[j], acc[i][j], 0, 0, 0);
                acc[i][j] = __builtin_amdgcn_mfma_f32_16x16x32_bf16(fah[i], fbl[j], acc[i][j], 0, 0, 0);
            }
        __syncthreads();
    }
    // ---- epilogue: C/D layout col=lane&15, row=quad*4+reg (m89-verified) ----
    float bv[2], wsv[2], wdv[2], hwv[2];
#pragma unroll
    for (int j = 0; j < 2; ++j) {
        int gn = n0 + wn + j * 16 + lm;
        bv[j] = bias ? bias[gn] : 0.f;
        if (FATT) { wsv[j] = was[gn]; wdv[j] = wad[gn]; }
        if (HDOT) { hwv[j] = hw[gn]; }
    }
#pragma unroll
    for (int i = 0; i < 4; ++i) {
#pragma unroll
        for (int r = 0; r < 4; ++r) {
            int gm = m0 + i * 16 + lq * 4 + r;
            float vs = 0.f, vd = 0.f, hp = 0.f;
#pragma unroll
            for (int j = 0; j < 2; ++j) {
                int gn = n0 + wn + j * 16 + lm;
                float v = acc[i][j][r] + bv[j];
                if (ACT == 1) v = fmaxf(v, 0.f);
                if (ACT == 2) v = v > 0.f ? v : expm1f(v);
                if (!HDOT && gm < M) {
                    if (OSPLIT) {
                        long o = (long)gm * Cs + gn;
                        unsigned short h = f2bf(v);
                        Ch_g[o] = h;
                        Cl_g[o] = f2bf(v - bf2f(h));
                    } else {
                        C[(long)gm * (long)Cs + gn] = v;
                    }
                }
                if (FATT) { vs = fmaf(v, wsv[j], vs); vd = fmaf(v, wdv[j], vd); }
                if (HDOT) { hp = fmaf(v, hwv[j], hp); }
            }
            if (FATT) {
#pragma unroll
                for (int o = 8; o; o >>= 1) {
                    vs += __shfl_xor(vs, o);
                    vd += __shfl_xor(vd, o);
                }
                if (lm == 0 && gm < M) {
                    atomicAdd(oas + gm, vs);
                    atomicAdd(oad + gm, vd);
                }
            }
            if (HDOT) {
#pragma unroll
                for (int o = 8; o; o >>= 1) hp += __shfl_xor(hp, o);
                if (lm == 0 && gm < M) {
                    float add = hp;
                    if (n0 == 0 && wave == 0) add += hb[0];
                    atomicAdd(hout + gm, add);
                }
            }
        }
    }
}

// ---------------- CSR scans (both graphs) ----------------------------------
__device__ __forceinline__ void scan1_body(
    const int* cnt, int* off, int* bsum, int n, int b, int t)
{
    __shared__ int s[256];
    int i = b * 256 + t;
    int v = (i < n) ? cnt[i] : 0;
    s[t] = v;
    __syncthreads();
    for (int d = 1; d < 256; d <<= 1) {
        int u = (t >= d) ? s[t - d] : 0;
        __syncthreads();
        s[t] += u;
        __syncthreads();
    }
    if (i < n) off[i] = s[t] - v;
    if (t == 255) bsum[b] = s[255];
}

__global__ __launch_bounds__(256) void scan1both_kernel(
    const int* __restrict__ dcnt, int* __restrict__ doff, int* __restrict__ bsum_d, int ND, int nbd,
    const int* __restrict__ ccnt, int* __restrict__ coff, int* __restrict__ bsum_c, int NC)
{
    int b = blockIdx.x, t = threadIdx.x;
    if (b < nbd) scan1_body(dcnt, doff, bsum_d, ND, b, t);
    else         scan1_body(ccnt, coff, bsum_c, NC, b - nbd, t);
}

__device__ __forceinline__ void scan2_body(
    const int* bsum, int* bpre, int nb, int* off, int n, int t)
{
    __shared__ int s[256];
    int v = (t < nb) ? bsum[t] : 0;
    s[t] = v;
    __syncthreads();
    for (int d = 1; d < 256; d <<= 1) {
        int u = (t >= d) ? s[t - d] : 0;
        __syncthreads();
        s[t] += u;
        __syncthreads();
    }
    if (t < nb) bpre[t] = s[t] - v;
    if (t == 255) off[n] = s[255];
}

__global__ __launch_bounds__(256) void scan2both_kernel(
    const int* __restrict__ bsum_d, int* __restrict__ bpre_d, int nbd, int* __restrict__ doff, int ND,
    const int* __restrict__ bsum_c, int* __restrict__ bpre_c, int nbc, int* __restrict__ coff, int NC)
{
    int t = threadIdx.x;
    if (blockIdx.x == 0) scan2_body(bsum_d, bpre_d, nbd, doff, ND, t);
    else                 scan2_body(bsum_c, bpre_c, nbc, coff, NC, t);
}

__global__ __launch_bounds__(256) void scan3both_kernel(
    int* __restrict__ doff, int* __restrict__ dcur, const int* __restrict__ bpre_d, int ND, int nbd,
    int* __restrict__ coff, int* __restrict__ ccur, const int* __restrict__ bpre_c, int NC)
{
    int b = blockIdx.x, t = threadIdx.x;
    if (b < nbd) {
        int i = b * 256 + t;
        if (i < ND) {
            int v = doff[i] + bpre_d[b];
            doff[i] = v;
            dcur[i] = v;
        }
    } else {
        int i = (b - nbd) * 256 + t;
        if (i < NC) {
            int v = coff[i] + bpre_c[b - nbd];
            coff[i] = v;
            ccur[i] = v;
        }
    }
}

__global__ __launch_bounds__(256) void scatter2_kernel(
    const int* __restrict__ dsrc, const int* __restrict__ ddst,
    int* __restrict__ dcur, int* __restrict__ debuf, int ED, int ND,
    const int* __restrict__ csrc, const int* __restrict__ cdst,
    int* __restrict__ ccur, int* __restrict__ cebuf, int EC, int NC)
{
    int t = blockIdx.x * 256 + threadIdx.x;
    int tot1 = ED + ND;
    if (t < tot1) {
        int s = t < ED ? dsrc[t] : (t - ED);
        int d = t < ED ? ddst[t] : (t - ED);
        int pos = atomicAdd(&dcur[d], 1);
        debuf[pos] = s;
    } else {
        int u = t - tot1;
        if (u < EC + NC) {
            int s = u < EC ? csrc[u] : (u - EC);
            int d = u < EC ? cdst[u] : (u - EC);
            int pos = atomicAdd(&ccur[d], 1);
            cebuf[pos] = s;
        }
    }
}

// ------------- fused softmax + aggregate, one WAVE per output row -----------
template<int EPI>
__global__ __launch_bounds__(256) void gat_agg3(
    const int* __restrict__ off, const int* __restrict__ ebuf,
    const float* __restrict__ as_, const float* __restrict__ ad_,
    const float* __restrict__ x, const float* __restrict__ bias,
    const int* __restrict__ dmap,
    float* __restrict__ outF, unsigned short* __restrict__ outH,
    unsigned short* __restrict__ outL, int nrows)
{
    int row = blockIdx.x * 4 + (threadIdx.x >> 6);
    int lane = threadIdx.x & 63;
    if (row >= nrows) return;
    int d = dmap ? dmap[row] : row;
    int lo = off[d], hi = off[d + 1];
    float adv = ad_[d];

    float m = -INFINITY;
    for (int p = lo + lane; p < hi; p += 64)
        m = fmaxf(m, lrelu(as_[ebuf[p]] + adv));
#pragma unroll
    for (int o = 32; o; o >>= 1) m = fmaxf(m, __shfl_xor(m, o));

    const float* xb = x + lane * 4;
    float4 acc = {0.f, 0.f, 0.f, 0.f};
    float psum = 0.f;
    for (int base = lo; base < hi; base += 64) {
        int cnt = min(64, hi - base);
        int s = 0;
        float ex = 0.f;
        if (lane < cnt) {
            s = ebuf[base + lane];
            ex = expf(lrelu(as_[s] + adv) - m);
        }
        psum += ex;
        for (int i = 0; i < cnt; ++i) {
            int si = __shfl(s, i);
            float ei = __shfl(ex, i);
            float4 v = *(const float4*)(xb + (long)si * 256);
            acc.x = fmaf(ei, v.x, acc.x);
            acc.y = fmaf(ei, v.y, acc.y);
            acc.z = fmaf(ei, v.z, acc.z);
            acc.w = fmaf(ei, v.w, acc.w);
        }
    }
#pragma unroll
    for (int o = 32; o; o >>= 1) psum += __shfl_xor(psum, o);
    float inv = 1.f / psum;

    long ob = (long)row * 256 + lane * 4;
    if (EPI == 1) {
        float r0 = fmaxf(acc.x * inv + bias[lane * 4 + 0], 0.f);
        float r1 = fmaxf(acc.y * inv + bias[lane * 4 + 1], 0.f);
        float r2 = fmaxf(acc.z * inv + bias[lane * 4 + 2], 0.f);
        float r3 = fmaxf(acc.w * inv + bias[lane * 4 + 3], 0.f);
        float4 r = {r0, r1, r2, r3};
        *(float4*)(outF + ob) = r;
    } else {
        float vv[4] = {acc.x * inv, acc.y * inv, acc.z * inv, acc.w * inv};
#pragma unroll
        for (int j = 0; j < 4; ++j) {
            unsigned short h = f2bf(vv[j]);
            outH[ob + j] = h;
            outL[ob + j] = f2bf(vv[j] - bf2f(h));
        }
    }
}

// comb right half, 4 rows per block: comb[i][256+c] = split(cfin[cidx[i]][c])
__global__ __launch_bounds__(256) void gather_cell_split4(
    const float* __restrict__ cfin, const int* __restrict__ cidx,
    unsigned short* __restrict__ combH, unsigned short* __restrict__ combL)
{
    int row = blockIdx.x * 4 + (threadIdx.x >> 6);
    int lane = threadIdx.x & 63;
    float4 v = *(const float4*)(cfin + (long)cidx[row] * 256 + lane * 4);
    long b = (long)row * 512 + 256 + lane * 4;
    float vv[4] = {v.x, v.y, v.z, v.w};
#pragma unroll
    for (int j = 0; j < 4; ++j) {
        unsigned short h = f2bf(vv[j]);
        combH[b + j] = h;
        combL[b + j] = f2bf(vv[j] - bf2f(h));
    }
}

// ------------------------------ orchestration -------------------------------
static inline dim3 mfma_grid64(int M, int N) {
    int ny = (M + 63) / 64;
    ny = (ny + 7) & ~7;
    return dim3(N / 128, ny);
}

extern "C" void kernel_launch(void* const* d_in, const int* in_sizes, int n_in,
                              void* d_out, int out_size, void* d_ws, size_t ws_size,
                              hipStream_t stream)
{
    const float* drug_x = (const float*)d_in[0];
    const float* cell_x = (const float*)d_in[1];
    const int* d_ei = (const int*)d_in[2];
    const int* c_ei = (const int*)d_in[3];
    const int* d_idx = (const int*)d_in[4];
    const int* c_idx = (const int*)d_in[5];
    const float* dW1 = (const float*)d_in[6];
    const float* db1 = (const float*)d_in[7];
    const float* cW1 = (const float*)d_in[8];
    const float* cb1 = (const float*)d_in[9];
    const float* cW2 = (const float*)d_in[10];
    const float* cb2 = (const float*)d_in[11];
    const float* gdW = (const float*)d_in[12];
    const float* gdas = (const float*)d_in[13];
    const float* gdad = (const float*)d_in[14];
    const float* gdb = (const float*)d_in[15];
    const float* g1W = (const float*)d_in[16];
    const float* g1as = (const float*)d_in[17];
    const float* g1ad = (const float*)d_in[18];
    const float* g1b = (const float*)d_in[19];
    const float* g2W = (const float*)d_in[20];
    const float* g2as = (const float*)d_in[21];
    const float* g2ad = (const float*)d_in[22];
    const float* g2b = (const float*)d_in[23];
    const float* rW1 = (const float*)d_in[24];
    const float* rb1 = (const float*)d_in[25];
    const float* rW2 = (const float*)d_in[26];
    const float* rb2 = (const float*)d_in[27];
    const float* rW3 = (const float*)d_in[28];
    const float* rb3 = (const float*)d_in[29];

    const int ND = in_sizes[0] / 128;     // 50000
    const int NC = in_sizes[1] / 735;     // 10000
    const int ED = in_sizes[2] / 2;       // 800000
    const int EC = in_sizes[3] / 2;       // 160000
    const int NB = in_sizes[4];           // 16384

    const int* d_src = d_ei;
    const int* d_dst = d_ei + ED;
    const int* c_src = c_ei;
    const int* c_dst = c_ei + EC;

    const size_t MB = 1ull << 20;
    const size_t KB = 1024;
    char* ws = (char*)d_ws;

    // ---- weight split region [0, 9MB) ----
    size_t wo = 0;
    auto walloc = [&](size_t elems) -> unsigned short* {
        unsigned short* p = (unsigned short*)(ws + wo);
        wo += ((elems * 2 + 255) & ~(size_t)255);
        return p;
    };
    unsigned short* dW1h = walloc(256 * 128);  unsigned short* dW1l = walloc(256 * 128);
    unsigned short* cW1h = walloc(1024 * 736); unsigned short* cW1l = walloc(1024 * 736);
    unsigned short* cW2h = walloc(256 * 1024); unsigned short* cW2l = walloc(256 * 1024);
    unsigned short* gdWh = walloc(256 * 256);  unsigned short* gdWl = walloc(256 * 256);
    unsigned short* g1Wh = walloc(1024 * 256); unsigned short* g1Wl = walloc(1024 * 256);
    unsigned short* g2Wh = walloc(256 * 1024); unsigned short* g2Wl = walloc(256 * 1024);
    unsigned short* rW1h = walloc(512 * 512);  unsigned short* rW1l = walloc(512 * 512);
    unsigned short* rW2h = walloc(512 * 512);  unsigned short* rW2l = walloc(512 * 512);

    // ---- small scratch (not zeroed) [9, 11MB) ----
    float* wa_ds  = (float*)(ws + 9 * MB);
    float* wa_dd  = (float*)(ws + 9 * MB + 4 * KB);
    float* wa_c1s = (float*)(ws + 9 * MB + 8 * KB);
    float* wa_c1d = (float*)(ws + 9 * MB + 12 * KB);
    int*   bsum_d = (int*)(ws + 9 * MB + 400 * KB);
    int*   bpre_d = (int*)(ws + 9 * MB + 404 * KB);
    int*   bsum_c = (int*)(ws + 9 * MB + 408 * KB);
    int*   bpre_c = (int*)(ws + 9 * MB + 412 * KB);
    int*   doff   = (int*)(ws + 9 * MB + 448 * KB);   // ND+1 ints
    int*   dcur   = (int*)(ws + 9 * MB + 704 * KB);
    int*   cebuf  = (int*)(ws + 10 * MB);              // EC+NC ints (~680KB)
    int*   coff   = (int*)(ws + 10 * MB + 768 * KB);   // NC+1 ints
    int*   ccur   = (int*)(ws + 10 * MB + 832 * KB);
    // ---- zero block [11MB, 11MB+1088KB): one memset covers all ----
    float* das    = (float*)(ws + 11 * MB);
    float* dad    = (float*)(ws + 11 * MB + 256 * KB);
    int*   dcnt   = (int*)(ws + 11 * MB + 512 * KB);
    int*   ccnt   = (int*)(ws + 11 * MB + 768 * KB);
    float* cas    = (float*)(ws + 11 * MB + 832 * KB);
    float* cad    = (float*)(ws + 11 * MB + 896 * KB);
    float* cas2   = (float*)(ws + 11 * MB + 960 * KB);
    float* cad2   = (float*)(ws + 11 * MB + 1024 * KB);
    int*   debuf  = (int*)(ws + 12 * MB + 256 * KB);   // ED+ND ints -> ends ~15.7MB

    // ---- big buffers (liveness-checked) ----
    float* dbuf  = (float*)(ws + 16 * MB);                    // d0 [ND,256] [16,65)
    unsigned short* aggdh = (unsigned short*)(ws + 66 * MB);  // [NB,256]
    unsigned short* aggdl = (unsigned short*)(ws + 75 * MB);
    unsigned short* combh = (unsigned short*)(ws + 84 * MB);  // [NB,512]
    unsigned short* combl = (unsigned short*)(ws + 101 * MB);
    unsigned short* c0h = (unsigned short*)(ws + 16 * MB);    // (dbuf dead)
    unsigned short* c0l = (unsigned short*)(ws + 36 * MB);
    float* c1b   = (float*)(ws + 118 * MB);                   // [NC,256]
    unsigned short* aggch = (unsigned short*)(ws + 129 * MB);
    unsigned short* aggcl = (unsigned short*)(ws + 135 * MB);
    unsigned short* c2h = (unsigned short*)(ws + 16 * MB);    // (c0 dead)
    unsigned short* c2l = (unsigned short*)(ws + 36 * MB);
    float* xc2   = (float*)(ws + 118 * MB);                   // (c1 dead)
    float* cfin  = (float*)(ws + 141 * MB);
    unsigned short* h1h = (unsigned short*)(ws + 16 * MB);    // (c2 dead)
    unsigned short* h1l = (unsigned short*)(ws + 33 * MB);
    unsigned short* cxh = (unsigned short*)(ws + 152 * MB);   // cell_x split
    unsigned short* cxl = (unsigned short*)(ws + 167 * MB);

    // ====================== memsets (2 total) ==============================
    hipMemsetAsync(ws + 11 * MB, 0, 1088 * KB, stream);
    hipMemsetAsync(d_out, 0, (size_t)NB * 4, stream);

    // ================= merged prepass (1 launch) ===========================
    SJobs js;
    js.j[0] = {dW1, dW1h, dW1l, 128, 256, 128, 0};
    js.j[1] = {cW1, cW1h, cW1l, 735, 1024, 736, 32};
    js.j[2] = {cW2, cW2h, cW2l, 1024, 256, 1024, 768};
    js.j[3] = {gdW, gdWh, gdWl, 256, 256, 256, 1024};
    js.j[4] = {g1W, g1Wh, g1Wl, 256, 1024, 256, 1088};
    js.j[5] = {g2W, g2Wh, g2Wl, 1024, 256, 1024, 1344};
    js.j[6] = {rW1, rW1h, rW1l, 512, 512, 512, 1600};
    js.j[7] = {rW2, rW2h, rW2l, 512, 512, 512, 1856};
    prepass_all<<<2112 + NC + 1024, 256, 0, stream>>>(
        js, 2112, cell_x, cxh, cxl, NC,
        gdW, gdas, gdad, wa_ds, wa_dd,
        g1W, g1as, g1ad, wa_c1s, wa_c1d);

    // ============ d0 GEMM + CSR histogram (merged, independent) ============
    {
        int nblk = 2 * ((ND + 63) / 64);
        int htot = (ED + ND) + (EC + NC);
        int hblk = (htot + 255) / 256;
        d0_hist<<<nblk + hblk, 256, 0, stream>>>(
            drug_x, dW1h, dW1l, db1, wa_ds, wa_dd, dbuf, das, dad, ND, nblk,
            d_dst, dcnt, ED, ND, c_dst, ccnt, EC, NC);
    }
    // ================= CSR scans + scatter =================================
    {
        int nbd = (ND + 255) / 256, nbc = (NC + 255) / 256;
        int tot = (ED + ND) + (EC + NC);
        scan1both_kernel<<<nbd + nbc, 256, 0, stream>>>(
            dcnt, doff, bsum_d, ND, nbd, ccnt, coff, bsum_c, NC);
        scan2both_kernel<<<2, 256, 0, stream>>>(
            bsum_d, bpre_d, nbd, doff, ND, bsum_c, bpre_c, nbc, coff, NC);
        scan3both_kernel<<<nbd + nbc, 256, 0, stream>>>(
            doff, dcur, bpre_d, ND, nbd, coff, ccur, bpre_c, NC);
        scatter2_kernel<<<(tot + 255) / 256, 256, 0, stream>>>(
            d_src, d_dst, dcur, debuf, ED, ND,
            c_src, c_dst, ccur, cebuf, EC, NC);
    }

    // ======================= drug path (batch-sparse) =======================
    gat_agg3<0><<<(NB + 3) / 4, 256, 0, stream>>>(doff, debuf, das, dad, dbuf, nullptr,
                                                  d_idx, nullptr, aggdh, aggdl, NB);
    gemm2<1, 1, 0, 0><<<mfma_grid64(NB, 256), 256, 0, stream>>>(
        aggdh, aggdl, gdWh, gdWl, gdb, nullptr, combh, combl,
        nullptr, nullptr, nullptr, nullptr, nullptr, nullptr, nullptr,
        NB, 256, 256, 256, 512);

    // ======================= cell path =======================
    gemm2<1, 1, 0, 0><<<mfma_grid64(NC, 1024), 256, 0, stream>>>(
        cxh, cxl, cW1h, cW1l, cb1, nullptr, c0h, c0l,
        nullptr, nullptr, nullptr, nullptr, nullptr, nullptr, nullptr,
        NC, 736, 1024, 736, 1024);
    gemm2<1, 0, 1, 0><<<mfma_grid64(NC, 256), 256, 0, stream>>>(
        c0h, c0l, cW2h, cW2l, cb2, c1b, nullptr, nullptr,
        wa_c1s, wa_c1d, cas, cad, nullptr, nullptr, nullptr,
        NC, 1024, 256, 1024, 256);
    gat_agg3<0><<<(NC + 3) / 4, 256, 0, stream>>>(coff, cebuf, cas, cad, c1b, nullptr,
                                                  nullptr, nullptr, aggch, aggcl, NC);
    gemm2<1, 1, 0, 0><<<mfma_grid64(NC, 1024), 256, 0, stream>>>(
        aggch, aggcl, g1Wh, g1Wl, g1b, nullptr, c2h, c2l,
        nullptr, nullptr, nullptr, nullptr, nullptr, nullptr, nullptr,
        NC, 256, 1024, 256, 1024);
    // g2 with fused att into fresh cas2/cad2 (pre-zeroed; no mid-chain memset)
    gemm2<0, 0, 1, 0><<<mfma_grid64(NC, 256), 256, 0, stream>>>(
        c2h, c2l, g2Wh, g2Wl, nullptr, xc2, nullptr, nullptr,
        g2as, g2ad, cas2, cad2, nullptr, nullptr, nullptr,
        NC, 1024, 256, 1024, 256);
    gat_agg3<1><<<(NC + 3) / 4, 256, 0, stream>>>(coff, cebuf, cas2, cad2, xc2, g2b,
                                                  nullptr, cfin, nullptr, nullptr, NC);

    // ======================= head =======================
    gather_cell_split4<<<NB / 4, 256, 0, stream>>>(cfin, c_idx, combh, combl);
    gemm2<2, 1, 0, 0><<<mfma_grid64(NB, 512), 256, 0, stream>>>(
        combh, combl, rW1h, rW1l, rb1, nullptr, h1h, h1l,
        nullptr, nullptr, nullptr, nullptr, nullptr, nullptr, nullptr,
        NB, 512, 512, 512, 512);
    gemm2<2, 0, 0, 1><<<mfma_grid64(NB, 512), 256, 0, stream>>>(
        h1h, h1l, rW2h, rW2l, rb2, nullptr, nullptr, nullptr,
        nullptr, nullptr, nullptr, nullptr, rW3, rb3, (float*)d_out,
        NB, 512, 512, 512, 512);
}